// Round 4
// baseline (1092.910 us; speedup 1.0000x reference)
//
#include <hip/hip_runtime.h>
#include <math.h>

#define BB 2
#define LL 2048
#define DD 1024
#define HH 16
#define SCALE 0.03125f   // 1/sqrt(1024)

#define ATTN_ELEMS ((size_t)BB * LL * DD)           // 4,194,304 fp32

typedef unsigned short u16;
typedef __attribute__((ext_vector_type(8))) short bf16x8;
typedef __attribute__((ext_vector_type(4))) short s16x4;
typedef __attribute__((ext_vector_type(4))) float f32x4;

__device__ __forceinline__ u16 f2bf_rne(float f) {
    union { float f; unsigned u; } c; c.f = f;
    unsigned u = c.u;
    u += 0x7fffu + ((u >> 16) & 1u);
    return (u16)(u >> 16);
}

// fp32 -> bf16 hi (truncate) + bf16 lo (RNE of residual); x ≈ hi+lo, |err| ≲ 2^-17|x|
__device__ __forceinline__ void splitbf(float x, short& h, short& l) {
    union { float f; unsigned u; } c; c.f = x;
    unsigned uh = c.u & 0xFFFF0000u;
    h = (short)(uh >> 16);
    union { unsigned u; float f; } ch; ch.u = uh;
    l = (short)f2bf_rne(x - ch.f);
}

// Branchless stable insert of (cv,ci) into descending-sorted 8-list.
// Precondition: cv > tv[7]. Candidates arrive in ascending index order.
__device__ __forceinline__ void insert8(float (&tv)[8], int (&ti)[8], float cv, int ci) {
    bool g0 = cv > tv[0], g1 = cv > tv[1], g2 = cv > tv[2], g3 = cv > tv[3],
         g4 = cv > tv[4], g5 = cv > tv[5], g6 = cv > tv[6];
    tv[7] = g6 ? tv[6] : cv;                 ti[7] = g6 ? ti[6] : ci;
    tv[6] = g5 ? tv[5] : (g6 ? cv : tv[6]);  ti[6] = g5 ? ti[5] : (g6 ? ci : ti[6]);
    tv[5] = g4 ? tv[4] : (g5 ? cv : tv[5]);  ti[5] = g4 ? ti[4] : (g5 ? ci : ti[5]);
    tv[4] = g3 ? tv[3] : (g4 ? cv : tv[4]);  ti[4] = g3 ? ti[3] : (g4 ? ci : ti[4]);
    tv[3] = g2 ? tv[2] : (g3 ? cv : tv[3]);  ti[3] = g2 ? ti[2] : (g3 ? ci : ti[3]);
    tv[2] = g1 ? tv[1] : (g2 ? cv : tv[2]);  ti[2] = g1 ? ti[1] : (g2 ? ci : ti[2]);
    tv[1] = g0 ? tv[0] : (g1 ? cv : tv[1]);  ti[1] = g0 ? ti[0] : (g1 ? ci : ti[1]);
    tv[0] = g0 ? cv : tv[0];                 ti[0] = g0 ? ci : ti[0];
}

// Tie-aware variant: composite order (value desc, index asc).
// Precondition: (cv,ci) outranks slot 7.
__device__ __forceinline__ void insert8t(float (&tv)[8], int (&ti)[8], float cv, int ci) {
    bool g0 = cv > tv[0] || (cv == tv[0] && ci < ti[0]);
    bool g1 = cv > tv[1] || (cv == tv[1] && ci < ti[1]);
    bool g2 = cv > tv[2] || (cv == tv[2] && ci < ti[2]);
    bool g3 = cv > tv[3] || (cv == tv[3] && ci < ti[3]);
    bool g4 = cv > tv[4] || (cv == tv[4] && ci < ti[4]);
    bool g5 = cv > tv[5] || (cv == tv[5] && ci < ti[5]);
    bool g6 = cv > tv[6] || (cv == tv[6] && ci < ti[6]);
    tv[7] = g6 ? tv[6] : cv;                 ti[7] = g6 ? ti[6] : ci;
    tv[6] = g5 ? tv[5] : (g6 ? cv : tv[6]);  ti[6] = g5 ? ti[5] : (g6 ? ci : ti[6]);
    tv[5] = g4 ? tv[4] : (g5 ? cv : tv[5]);  ti[5] = g4 ? ti[4] : (g5 ? ci : ti[5]);
    tv[4] = g3 ? tv[3] : (g4 ? cv : tv[4]);  ti[4] = g3 ? ti[3] : (g4 ? ci : ti[4]);
    tv[3] = g2 ? tv[2] : (g3 ? cv : tv[3]);  ti[3] = g2 ? ti[2] : (g3 ? ci : ti[3]);
    tv[2] = g1 ? tv[1] : (g2 ? cv : tv[2]);  ti[2] = g1 ? ti[1] : (g2 ? ci : ti[2]);
    tv[1] = g0 ? tv[0] : (g1 ? cv : tv[1]);  ti[1] = g0 ? ti[0] : (g1 ? ci : ti[1]);
    tv[0] = g0 ? cv : tv[0];                 ti[0] = g0 ? ci : ti[0];
}

// Branchless stable insert into descending-sorted 12-list (precondition cv > tv[11]).
__device__ __forceinline__ void insert12(float (&tv)[12], int (&ti)[12], float cv, int ci) {
    bool g0 = cv > tv[0], g1 = cv > tv[1], g2 = cv > tv[2], g3 = cv > tv[3],
         g4 = cv > tv[4], g5 = cv > tv[5], g6 = cv > tv[6], g7 = cv > tv[7],
         g8 = cv > tv[8], g9 = cv > tv[9], g10 = cv > tv[10];
    tv[11] = g10 ? tv[10] : cv;                 ti[11] = g10 ? ti[10] : ci;
    tv[10] = g9 ? tv[9] : (g10 ? cv : tv[10]);  ti[10] = g9 ? ti[9] : (g10 ? ci : ti[10]);
    tv[9]  = g8 ? tv[8] : (g9 ? cv : tv[9]);    ti[9]  = g8 ? ti[8] : (g9 ? ci : ti[9]);
    tv[8]  = g7 ? tv[7] : (g8 ? cv : tv[8]);    ti[8]  = g7 ? ti[7] : (g8 ? ci : ti[8]);
    tv[7]  = g6 ? tv[6] : (g7 ? cv : tv[7]);    ti[7]  = g6 ? ti[6] : (g7 ? ci : ti[7]);
    tv[6]  = g5 ? tv[5] : (g6 ? cv : tv[6]);    ti[6]  = g5 ? ti[5] : (g6 ? ci : ti[6]);
    tv[5]  = g4 ? tv[4] : (g5 ? cv : tv[5]);    ti[5]  = g4 ? ti[4] : (g5 ? ci : ti[5]);
    tv[4]  = g3 ? tv[3] : (g4 ? cv : tv[4]);    ti[4]  = g3 ? ti[3] : (g4 ? ci : ti[4]);
    tv[3]  = g2 ? tv[2] : (g3 ? cv : tv[3]);    ti[3]  = g2 ? ti[2] : (g3 ? ci : ti[3]);
    tv[2]  = g1 ? tv[1] : (g2 ? cv : tv[2]);    ti[2]  = g1 ? ti[1] : (g2 ? ci : ti[2]);
    tv[1]  = g0 ? tv[0] : (g1 ? cv : tv[1]);    ti[1]  = g0 ? ti[0] : (g1 ? ci : ti[1]);
    tv[0]  = g0 ? cv : tv[0];                   ti[0]  = g0 ? ci : ti[0];
}

// Merge four descending-sorted 8-lists -> top-8 (value desc, index asc on ties).
__device__ __forceinline__ void merge4(
    const float* v0, const int* i0, const float* v1, const int* i1,
    const float* v2, const int* i2, const float* v3, const int* i3,
    float* ov, int* oi)
{
    int p0 = 0, p1 = 0, p2 = 0, p3 = 0;
    #pragma unroll
    for (int s = 0; s < 8; ++s) {
        float a0 = v0[p0], a1 = v1[p1], a2 = v2[p2], a3 = v3[p3];
        int   b0 = i0[p0], b1 = i1[p1], b2 = i2[p2], b3 = i3[p3];
        float bv = a0; int bi = b0; int bc = 0;
        if (a1 > bv || (a1 == bv && b1 < bi)) { bv = a1; bi = b1; bc = 1; }
        if (a2 > bv || (a2 == bv && b2 < bi)) { bv = a2; bi = b2; bc = 2; }
        if (a3 > bv || (a3 == bv && b3 < bi)) { bv = a3; bi = b3; bc = 3; }
        p0 += (bc == 0); p1 += (bc == 1); p2 += (bc == 2); p3 += (bc == 3);
        ov[s] = bv; oi[s] = bi;
    }
}

// ===========================================================================
// FAST PATH (ws >= 36 MB)
// ===========================================================================

// K fp32 -> split-bf16, stored in MFMA fragment layout per (b,h):
// shorts offset within head = s*1024 + c*512 + qd*128 + li*8  (head stride 131072)
__global__ __launch_bounds__(256) void prep_k_kernel(
    const float* __restrict__ k, u16* __restrict__ khi, u16* __restrict__ klo)
{
    int gid = blockIdx.x * 256 + threadIdx.x;          // 0 .. 524287
    int li   = gid & 15;
    int qd   = (gid >> 4) & 3;
    int c    = (gid >> 6) & 1;
    int s    = (gid >> 7) & 127;
    int head = gid >> 14;                              // 0 .. 31
    int b = head >> 4, h = head & 15;
    const float* src = k + ((size_t)(b * LL + s * 16 + li)) * DD + h * 64 + c * 32 + qd * 8;
    float x[8];
    *(f32x4*)x       = *(const f32x4*)src;
    *(f32x4*)(x + 4) = *(const f32x4*)(src + 4);
    bf16x8 h8, l8;
    #pragma unroll
    for (int e = 0; e < 8; ++e) { short hh, ll; splitbf(x[e], hh, ll); h8[e] = hh; l8[e] = ll; }
    *(bf16x8*)&khi[(size_t)gid * 8] = h8;
    *(bf16x8*)&klo[(size_t)gid * 8] = l8;
}

// W fp32 -> split-bf16 fragment layout:
// shorts offset = nb*65536 + kc*8192 + nt*2048 + c*512 + qd*128 + li*8
__global__ __launch_bounds__(256) void prep_w_kernel(
    const float* __restrict__ w, u16* __restrict__ whi, u16* __restrict__ wlo)
{
    int gid = blockIdx.x * 256 + threadIdx.x;          // 0 .. 131071
    int li = gid & 15;
    int qd = (gid >> 4) & 3;
    int c  = (gid >> 6) & 3;
    int nt = (gid >> 8) & 3;
    int kc = (gid >> 10) & 7;
    int nb = gid >> 13;                                // 0 .. 15
    const float* src = w + (size_t)(nb * 64 + nt * 16 + li) * DD + kc * 128 + c * 32 + qd * 8;
    float x[8];
    *(f32x4*)x       = *(const f32x4*)src;
    *(f32x4*)(x + 4) = *(const f32x4*)(src + 4);
    bf16x8 h8, l8;
    #pragma unroll
    for (int e = 0; e < 8; ++e) { short hh, ll; splitbf(x[e], hh, ll); h8[e] = hh; l8[e] = ll; }
    *(bf16x8*)&whi[(size_t)gid * 8] = h8;
    *(bf16x8*)&wlo[(size_t)gid * 8] = l8;
}

// Fused attention, fast path v4: group-max scan with a real register pipeline.
// __launch_bounds__(256,4) gives the allocator the full 128-VGPR budget (4
// waves/SIMD = the grid-imposed co-residency) so the 1-deep K-fragment
// prefetch actually stays in flight; unroll-2 rotates stages by renaming.
// P3 rescore: Q row hoisted to 16 f32x4 regs, candidates processed in pairs
// (8 independent FMA chains). Numerics identical to v3 (same fp32 op order,
// same insertion sequence). s2 rows padded to 9 to kill bank conflicts.
__global__ __launch_bounds__(256, 4) void attn_fast_kernel(
    const float* __restrict__ q, const float* __restrict__ k, const float* __restrict__ v,
    const u16* __restrict__ khi_g, const u16* __restrict__ klo_g,
    float* __restrict__ aw, u16* __restrict__ chi, u16* __restrict__ clo)
{
    // bijective XCD swizzle: blocks of one head cluster on one XCD.
    const int swz  = (blockIdx.x & 7) * 128 + (blockIdx.x >> 3);
    const int qt   = swz & 31;
    const int h    = (swz >> 5) & 15;
    const int b    = swz >> 9;
    const int t    = threadIdx.x;
    const int wv   = t >> 6;
    const int lane = t & 63;
    const int li   = lane & 15;
    const int quad = lane >> 4;

    // LDS arena (21504 B) with phase overlays:
    //  [0,1536)      gsel u16[64][12]      (P1 write, P3 read)
    //  [1536,13824)  dv f32[64][48]        (P0/P1) -> s2v f32[256][9] @1536 (P3/P4)
    //  [13824,19968) dg u16[64][48]        (P0/P1) -> s2i u16[256][9] @13824 (P3/P4)
    //  [18432,20480) wrow f32[64][8]       (P4 write, P5 read; dg dead, s2i ends @18432)
    //  [20480,21504) wix u16[64][8]        (P4 write, P5 read)
    __shared__ __align__(16) char arena[21504];
    u16*   gsel = (u16*)(arena);
    float* dv   = (float*)(arena + 1536);
    u16*   dg   = (u16*)(arena + 13824);
    float* s2v  = (float*)(arena + 1536);
    u16*   s2i  = (u16*)(arena + 13824);
    float* wrow = (float*)(arena + 18432);
    u16*   wixs = (u16*)(arena + 20480);

    f32x4* awz = (f32x4*)(aw + (((size_t)(b * HH + h) * LL) + (size_t)qt * 64) * LL);
    const f32x4 zero4 = {0.f, 0.f, 0.f, 0.f};

    // Q fragments (split-bf16). Lane data = Q[row wv*16+li][dims quad*8..] = B-operand col li.
    bf16x8 qh0, ql0, qh1, ql1;
    {
        const float* qrow = q + ((size_t)(b * LL + qt * 64 + wv * 16 + li)) * DD + h * 64;
        float x[8];
        *(f32x4*)x       = *(const f32x4*)(qrow + quad * 8);
        *(f32x4*)(x + 4) = *(const f32x4*)(qrow + quad * 8 + 4);
        #pragma unroll
        for (int e = 0; e < 8; ++e) { short hh, ll; splitbf(x[e], hh, ll); qh0[e] = hh; ql0[e] = ll; }
        *(f32x4*)x       = *(const f32x4*)(qrow + 32 + quad * 8);
        *(f32x4*)(x + 4) = *(const f32x4*)(qrow + 32 + quad * 8 + 4);
        #pragma unroll
        for (int e = 0; e < 8; ++e) { short hh, ll; splitbf(x[e], hh, ll); qh1[e] = hh; ql1[e] = ll; }
    }

    // Per-lane top-12 GROUPS for q-row (wv*16 + li). Group key gk = sp*32 + quad*4;
    // its 8 candidates are k = gk + (e>>2)*16 + (e&3), e=0..7.
    float tv[12]; int tg[12];
    #pragma unroll
    for (int s = 0; s < 12; ++s) { tv[s] = -INFINITY; tg[s] = 0; }

    const u16* khb = khi_g + (size_t)(b * HH + h) * 131072 + (size_t)lane * 8;
    const u16* klb = klo_g + (size_t)(b * HH + h) * 131072 + (size_t)lane * 8;

    // preload pair 0 (steps 0,1)
    bf16x8 Ah0 = *(const bf16x8*)(khb);
    bf16x8 Ah1 = *(const bf16x8*)(khb + 512);
    bf16x8 Al0 = *(const bf16x8*)(klb);
    bf16x8 Al1 = *(const bf16x8*)(klb + 512);
    bf16x8 Bh0 = *(const bf16x8*)(khb + 1024);
    bf16x8 Bh1 = *(const bf16x8*)(khb + 1536);
    bf16x8 Bl0 = *(const bf16x8*)(klb + 1024);
    bf16x8 Bl1 = *(const bf16x8*)(klb + 1536);

    #pragma unroll 2
    for (int sp = 0; sp < 64; ++sp) {
        const int spn = (sp + 1) & 63;            // wraps (harmless re-read)
        const size_t off = (size_t)spn * 2048;
        bf16x8 NAh0 = *(const bf16x8*)(khb + off);
        bf16x8 NAh1 = *(const bf16x8*)(khb + off + 512);
        bf16x8 NAl0 = *(const bf16x8*)(klb + off);
        bf16x8 NAl1 = *(const bf16x8*)(klb + off + 512);
        bf16x8 NBh0 = *(const bf16x8*)(khb + off + 1024);
        bf16x8 NBh1 = *(const bf16x8*)(khb + off + 1536);
        bf16x8 NBl0 = *(const bf16x8*)(klb + off + 1024);
        bf16x8 NBl1 = *(const bf16x8*)(klb + off + 1536);

        awz[sp * 512 + t]       = zero4;          // zero-fill rides along
        awz[sp * 512 + 256 + t] = zero4;

        f32x4 c4a = {0,0,0,0}, c4b = {0,0,0,0}, d4a = {0,0,0,0}, d4b = {0,0,0,0};
        c4a = __builtin_amdgcn_mfma_f32_16x16x32_bf16(Ah0, qh0, c4a, 0, 0, 0);
        c4b = __builtin_amdgcn_mfma_f32_16x16x32_bf16(Ah1, qh1, c4b, 0, 0, 0);
        d4a = __builtin_amdgcn_mfma_f32_16x16x32_bf16(Bh0, qh0, d4a, 0, 0, 0);
        d4b = __builtin_amdgcn_mfma_f32_16x16x32_bf16(Bh1, qh1, d4b, 0, 0, 0);
        c4a = __builtin_amdgcn_mfma_f32_16x16x32_bf16(Al0, qh0, c4a, 0, 0, 0);
        c4b = __builtin_amdgcn_mfma_f32_16x16x32_bf16(Al1, qh1, c4b, 0, 0, 0);
        d4a = __builtin_amdgcn_mfma_f32_16x16x32_bf16(Bl0, qh0, d4a, 0, 0, 0);
        d4b = __builtin_amdgcn_mfma_f32_16x16x32_bf16(Bl1, qh1, d4b, 0, 0, 0);
        c4a = __builtin_amdgcn_mfma_f32_16x16x32_bf16(Ah0, ql0, c4a, 0, 0, 0);
        c4b = __builtin_amdgcn_mfma_f32_16x16x32_bf16(Ah1, ql1, c4b, 0, 0, 0);
        d4a = __builtin_amdgcn_mfma_f32_16x16x32_bf16(Bh0, ql0, d4a, 0, 0, 0);
        d4b = __builtin_amdgcn_mfma_f32_16x16x32_bf16(Bh1, ql1, d4b, 0, 0, 0);

        float s0 = c4a[0] + c4b[0], s1 = c4a[1] + c4b[1];
        float s2 = c4a[2] + c4b[2], s3 = c4a[3] + c4b[3];
        float s4 = d4a[0] + d4b[0], s5 = d4a[1] + d4b[1];
        float s6 = d4a[2] + d4b[2], s7 = d4a[3] + d4b[3];
        float m = fmaxf(fmaxf(fmaxf(s0, s1), fmaxf(s2, s3)),
                        fmaxf(fmaxf(s4, s5), fmaxf(s6, s7)));
        if (m > tv[11]) insert12(tv, tg, m, sp * 32 + quad * 4);

        Ah0 = NAh0; Ah1 = NAh1; Al0 = NAl0; Al1 = NAl1;
        Bh0 = NBh0; Bh1 = NBh1; Bl0 = NBl0; Bl1 = NBl1;
    }

    // ---- P0 dump per-lane sorted group lists ----
    {
        const int row = wv * 16 + li;
        #pragma unroll
        for (int s = 0; s < 12; ++s) {
            dv[row * 48 + quad * 12 + s] = tv[s];
            dg[row * 48 + quad * 12 + s] = (u16)tg[s];
        }
    }
    __syncthreads();

    // ---- P1: merge 4 sorted 12-lists -> top-12 groups per row ----
    if (t < 64) {
        const float* v0 = &dv[t * 48];       const u16* i0 = &dg[t * 48];
        const float* v1 = &dv[t * 48 + 12];  const u16* i1 = &dg[t * 48 + 12];
        const float* v2 = &dv[t * 48 + 24];  const u16* i2 = &dg[t * 48 + 24];
        const float* v3 = &dv[t * 48 + 36];  const u16* i3 = &dg[t * 48 + 36];
        int p0 = 0, p1 = 0, p2 = 0, p3 = 0;
        #pragma unroll
        for (int s = 0; s < 12; ++s) {
            float a0 = v0[p0], a1 = v1[p1], a2 = v2[p2], a3 = v3[p3];
            int   b0 = i0[p0], b1 = i1[p1], b2 = i2[p2], b3 = i3[p3];
            float bv = a0; int bi = b0; int bc = 0;
            if (a1 > bv || (a1 == bv && b1 < bi)) { bv = a1; bi = b1; bc = 1; }
            if (a2 > bv || (a2 == bv && b2 < bi)) { bv = a2; bi = b2; bc = 2; }
            if (a3 > bv || (a3 == bv && b3 < bi)) { bv = a3; bi = b3; bc = 3; }
            p0 += (bc == 0); p1 += (bc == 1); p2 += (bc == 2); p3 += (bc == 3);
            gsel[t * 12 + s] = (u16)bi;
        }
    }
    __syncthreads();

    // ---- P3: exact rescore of 96 candidates/row, paired for ILP ----
    {
        const int row = t >> 2, p = t & 3;
        const float* qp = q + ((size_t)(b * LL + qt * 64 + row)) * DD + h * 64;
        f32x4 qr[16];
        #pragma unroll
        for (int d4 = 0; d4 < 16; ++d4) qr[d4] = *(const f32x4*)(qp + d4 * 4);
        float tv8[8]; int ti8[8];
        #pragma unroll
        for (int s = 0; s < 8; ++s) { tv8[s] = -INFINITY; ti8[s] = 0x7fffffff; }
        for (int jj = 0; jj < 24; jj += 2) {
            // j = p*24 + jj; p*24 % 8 == 0 so group index = p*3 + jj/8, e = jj&7.
            int gk = (int)gsel[row * 12 + p * 3 + (jj >> 3)];
            int e  = jj & 7;
            int k0 = gk + ((e >> 2) << 4) + (e & 3);   // e even -> pair is k0, k0+1
            int k1 = k0 + 1;
            const float* kp0 = k + ((size_t)(b * LL + k0)) * DD + h * 64;
            const float* kp1 = k + ((size_t)(b * LL + k1)) * DD + h * 64;
            float a0 = 0.f, a1 = 0.f, a2 = 0.f, a3 = 0.f;
            float b0 = 0.f, b1 = 0.f, b2 = 0.f, b3 = 0.f;
            #pragma unroll
            for (int d4 = 0; d4 < 16; ++d4) {
                f32x4 ka = *(const f32x4*)(kp0 + d4 * 4);
                f32x4 kb = *(const f32x4*)(kp1 + d4 * 4);
                a0 = fmaf(qr[d4][0], ka[0], a0);
                a1 = fmaf(qr[d4][1], ka[1], a1);
                a2 = fmaf(qr[d4][2], ka[2], a2);
                a3 = fmaf(qr[d4][3], ka[3], a3);
                b0 = fmaf(qr[d4][0], kb[0], b0);
                b1 = fmaf(qr[d4][1], kb[1], b1);
                b2 = fmaf(qr[d4][2], kb[2], b2);
                b3 = fmaf(qr[d4][3], kb[3], b3);
            }
            float sc0 = ((a0 + a1) + (a2 + a3)) * SCALE;
            float sc1 = ((b0 + b1) + (b2 + b3)) * SCALE;
            if (sc0 > tv8[7] || (sc0 == tv8[7] && k0 < ti8[7])) insert8t(tv8, ti8, sc0, k0);
            if (sc1 > tv8[7] || (sc1 == tv8[7] && k1 < ti8[7])) insert8t(tv8, ti8, sc1, k1);
        }
        #pragma unroll
        for (int s = 0; s < 8; ++s) {
            s2v[(row * 4 + p) * 9 + s] = tv8[s];
            s2i[(row * 4 + p) * 9 + s] = (u16)ti8[s];
        }
    }
    __syncthreads();

    // ---- P4: merge 4 top-8 lists -> exact top-8, softmax, scatter ----
    if (t < 64) {
        const float* v0 = &s2v[(t * 4 + 0) * 9]; const u16* i0 = &s2i[(t * 4 + 0) * 9];
        const float* v1 = &s2v[(t * 4 + 1) * 9]; const u16* i1 = &s2i[(t * 4 + 1) * 9];
        const float* v2 = &s2v[(t * 4 + 2) * 9]; const u16* i2 = &s2i[(t * 4 + 2) * 9];
        const float* v3 = &s2v[(t * 4 + 3) * 9]; const u16* i3 = &s2i[(t * 4 + 3) * 9];
        int p0 = 0, p1 = 0, p2 = 0, p3 = 0;
        float fv[8]; int fi[8];
        #pragma unroll
        for (int s = 0; s < 8; ++s) {
            float a0 = v0[p0], a1 = v1[p1], a2 = v2[p2], a3 = v3[p3];
            int   b0 = i0[p0], b1 = i1[p1], b2 = i2[p2], b3 = i3[p3];
            float bv = a0; int bi = b0; int bc = 0;
            if (a1 > bv || (a1 == bv && b1 < bi)) { bv = a1; bi = b1; bc = 1; }
            if (a2 > bv || (a2 == bv && b2 < bi)) { bv = a2; bi = b2; bc = 2; }
            if (a3 > bv || (a3 == bv && b3 < bi)) { bv = a3; bi = b3; bc = 3; }
            p0 += (bc == 0); p1 += (bc == 1); p2 += (bc == 2); p3 += (bc == 3);
            fv[s] = bv; fi[s] = bi;
        }
        float m = fv[0];
        float e0[8]; float sum = 0.f;
        #pragma unroll
        for (int s = 0; s < 8; ++s) { e0[s] = __expf(fv[s] - m); sum += e0[s]; }
        float inv = 1.0f / sum;
        float* awrow = aw + (((size_t)(b * HH + h) * LL) + (size_t)qt * 64 + t) * LL;
        #pragma unroll
        for (int s = 0; s < 8; ++s) {
            float w8 = e0[s] * inv;
            awrow[fi[s]] = w8;
            wrow[t * 8 + s] = w8; wixs[t * 8 + s] = (u16)fi[s];
        }
    }
    __syncthreads();

    // ---- P5: context = P @ V; emit split-bf16 directly ----
    const float* vbase = v + ((size_t)b * LL) * DD + h * 64;
    #pragma unroll
    for (int i = 0; i < 4; ++i) {
        int id = i * 256 + t;
        int row = id >> 4, seg = id & 15;
        f32x4 acc = {0.f, 0.f, 0.f, 0.f};
        #pragma unroll
        for (int s = 0; s < 8; ++s) {
            float ws = wrow[row * 8 + s];
            f32x4 vvv = *(const f32x4*)(vbase + (size_t)wixs[row * 8 + s] * DD + seg * 4);
            acc[0] = fmaf(ws, vvv[0], acc[0]);
            acc[1] = fmaf(ws, vvv[1], acc[1]);
            acc[2] = fmaf(ws, vvv[2], acc[2]);
            acc[3] = fmaf(ws, vvv[3], acc[3]);
        }
        size_t off = ((size_t)(b * LL + qt * 64 + row)) * DD + h * 64 + seg * 4;
        s16x4 h4, l4;
        #pragma unroll
        for (int j = 0; j < 4; ++j) { short hh, ll; splitbf(acc[j], hh, ll); h4[j] = hh; l4[j] = ll; }
        *(s16x4*)(chi + off) = h4;
        *(s16x4*)(clo + off) = l4;
    }
}

// Projection, fast path: A (ctx) and B (w) both pre-split; pure load + MFMA.
__global__ __launch_bounds__(256) void linear_fast_kernel(
    const u16* __restrict__ chi, const u16* __restrict__ clo,
    const u16* __restrict__ whi, const u16* __restrict__ wlo,
    const float* __restrict__ bias, float* __restrict__ out)
{
    const int bid  = blockIdx.x;
    const int nb   = bid & 15, mb = bid >> 4;
    const int t    = threadIdx.x;
    const int wv   = t >> 6;
    const int lane = t & 63;
    const int li   = lane & 15;
    const int quad = lane >> 4;

    f32x4 acc0 = {0.f,0.f,0.f,0.f}, acc1 = {0.f,0.f,0.f,0.f},
          acc2 = {0.f,0.f,0.f,0.f}, acc3 = {0.f,0.f,0.f,0.f};

    const u16* ah_row = chi + (size_t)(mb * 64 + wv * 16 + li) * DD + quad * 8;
    const u16* al_row = clo + (size_t)(mb * 64 + wv * 16 + li) * DD + quad * 8;
    const size_t wboff = (size_t)nb * 65536 + (size_t)lane * 8;

    for (int kc = 0; kc < 8; ++kc) {
        const u16* wb_h = whi + wboff + kc * 8192;
        const u16* wb_l = wlo + wboff + kc * 8192;
        #pragma unroll
        for (int c = 0; c < 4; ++c) {
            bf16x8 ah = *(const bf16x8*)(ah_row + kc * 128 + c * 32);
            bf16x8 al = *(const bf16x8*)(al_row + kc * 128 + c * 32);
            bf16x8 bh0 = *(const bf16x8*)(wb_h + c * 512);
            bf16x8 bl0 = *(const bf16x8*)(wb_l + c * 512);
            bf16x8 bh1 = *(const bf16x8*)(wb_h + 2048 + c * 512);
            bf16x8 bl1 = *(const bf16x8*)(wb_l + 2048 + c * 512);
            bf16x8 bh2 = *(const bf16x8*)(wb_h + 4096 + c * 512);
            bf16x8 bl2 = *(const bf16x8*)(wb_l + 4096 + c * 512);
            bf16x8 bh3 = *(const bf16x8*)(wb_h + 6144 + c * 512);
            bf16x8 bl3 = *(const bf16x8*)(wb_l + 6144 + c * 512);
            acc0 = __builtin_amdgcn_mfma_f32_16x16x32_bf16(ah, bh0, acc0, 0, 0, 0);
            acc0 = __builtin_amdgcn_mfma_f32_16x16x32_bf16(ah, bl0, acc0, 0, 0, 0);
            acc0 = __builtin_amdgcn_mfma_f32_16x16x32_bf16(al, bh0, acc0, 0, 0, 0);
            acc1 = __builtin_amdgcn_mfma_f32_16x16x32_bf16(ah, bh1, acc1, 0, 0, 0);
            acc1 = __builtin_amdgcn_mfma_f32_16x16x32_bf16(ah, bl1, acc1, 0, 0, 0);
            acc1 = __builtin_amdgcn_mfma_f32_16x16x32_bf16(al, bh1, acc1, 0, 0, 0);
            acc2 = __builtin_amdgcn_mfma_f32_16x16x32_bf16(ah, bh2, acc2, 0, 0, 0);
            acc2 = __builtin_amdgcn_mfma_f32_16x16x32_bf16(ah, bl2, acc2, 0, 0, 0);
            acc2 = __builtin_amdgcn_mfma_f32_16x16x32_bf16(al, bh2, acc2, 0, 0, 0);
            acc3 = __builtin_amdgcn_mfma_f32_16x16x32_bf16(ah, bh3, acc3, 0, 0, 0);
            acc3 = __builtin_amdgcn_mfma_f32_16x16x32_bf16(ah, bl3, acc3, 0, 0, 0);
            acc3 = __builtin_amdgcn_mfma_f32_16x16x32_bf16(al, bh3, acc3, 0, 0, 0);
        }
    }

    #pragma unroll
    for (int st = 0; st < 4; ++st) {
        f32x4 a = (st == 0) ? acc0 : (st == 1) ? acc1 : (st == 2) ? acc2 : acc3;
        int col = nb * 64 + st * 16 + li;
        float bb2 = bias[col];
        #pragma unroll
        for (int r = 0; r < 4; ++r)
            out[(size_t)(mb * 64 + wv * 16 + quad * 4 + r) * DD + col] = a[r] + bb2;
    }
}

// ===========================================================================
// FALLBACK PATH (unchanged from previous passing version)
// ===========================================================================

__global__ __launch_bounds__(256) void attn_kernel(
    const float* __restrict__ q, const float* __restrict__ k, const float* __restrict__ v,
    float* __restrict__ aw, float* __restrict__ ctx)
{
    const int bid  = blockIdx.x;
    const int qt   = bid & 31;
    const int h    = (bid >> 5) & 15;
    const int b    = bid >> 9;
    const int t    = threadIdx.x;
    const int wv   = t >> 6;
    const int lane = t & 63;
    const int li   = lane & 15;
    const int quad = lane >> 4;

    __shared__ __align__(16) char smA[32768];
    __shared__ float s2v[32][4][8];
    __shared__ int   s2i[32][4][8];
    __shared__ int   cidx[32][12];
    __shared__ float cs[32][12];
    __shared__ float wrow[64][8];
    __shared__ int   wix[64][8];
    u16* khi = (u16*)smA;
    u16* klo = (u16*)(smA + 16384);

    const float* kbase = k + ((size_t)b * LL) * DD + h * 64;
    f32x4* awz = (f32x4*)(aw + (((size_t)(b * HH + h) * LL) + (size_t)qt * 64) * LL);
    const f32x4 zero4 = {0.f, 0.f, 0.f, 0.f};

    bf16x8 qh0, ql0, qh1, ql1;
    {
        const float* qrow = q + ((size_t)(b * LL + qt * 64 + wv * 16 + li)) * DD + h * 64;
        float x[8];
        *(f32x4*)x       = *(const f32x4*)(qrow + quad * 8);
        *(f32x4*)(x + 4) = *(const f32x4*)(qrow + quad * 8 + 4);
        #pragma unroll
        for (int e = 0; e < 8; ++e) { short hh, ll; splitbf(x[e], hh, ll); qh0[e] = hh; ql0[e] = ll; }
        *(f32x4*)x       = *(const f32x4*)(qrow + 32 + quad * 8);
        *(f32x4*)(x + 4) = *(const f32x4*)(qrow + 32 + quad * 8 + 4);
        #pragma unroll
        for (int e = 0; e < 8; ++e) { short hh, ll; splitbf(x[e], hh, ll); qh1[e] = hh; ql1[e] = ll; }
    }

    float tv[4][8]; int tix[4][8];
    #pragma unroll
    for (int r = 0; r < 4; ++r)
        #pragma unroll
        for (int s = 0; s < 8; ++s) { tv[r][s] = -INFINITY; tix[r][s] = 0; }

    for (int iter = 0; iter < 16; ++iter) {
        __syncthreads();
        #pragma unroll
        for (int j = 0; j < 4; ++j) {
            int f   = j * 256 + t;
            int col = f >> 3;
            int c   = (f >> 2) & 1;
            int qd  = f & 3;
            const float* src = kbase + (size_t)(iter * 128 + col) * DD + c * 32 + qd * 8;
            float x[8];
            *(f32x4*)x       = *(const f32x4*)src;
            *(f32x4*)(x + 4) = *(const f32x4*)(src + 4);
            bf16x8 h8, l8;
            #pragma unroll
            for (int e = 0; e < 8; ++e) { short hh, ll; splitbf(x[e], hh, ll); h8[e] = hh; l8[e] = ll; }
            int off = (((col >> 4) * 2 + c) << 9) + (qd << 7) + ((col & 15) << 3);
            *(bf16x8*)&khi[off] = h8;
            *(bf16x8*)&klo[off] = l8;
        }
        #pragma unroll
        for (int i = 0; i < 8; ++i) awz[iter * 2048 + i * 256 + t] = zero4;
        __syncthreads();

        #pragma unroll
        for (int s = 0; s < 8; ++s) {
            int fo = s << 10;
            bf16x8 kh0 = *(bf16x8*)&khi[fo + (lane << 3)];
            bf16x8 kh1 = *(bf16x8*)&khi[fo + 512 + (lane << 3)];
            bf16x8 kl0 = *(bf16x8*)&klo[fo + (lane << 3)];
            bf16x8 kl1 = *(bf16x8*)&klo[fo + 512 + (lane << 3)];
            f32x4 c4 = {0.f, 0.f, 0.f, 0.f};
            c4 = __builtin_amdgcn_mfma_f32_16x16x32_bf16(qh0, kh0, c4, 0, 0, 0);
            c4 = __builtin_amdgcn_mfma_f32_16x16x32_bf16(qh1, kh1, c4, 0, 0, 0);
            c4 = __builtin_amdgcn_mfma_f32_16x16x32_bf16(qh0, kl0, c4, 0, 0, 0);
            c4 = __builtin_amdgcn_mfma_f32_16x16x32_bf16(qh1, kl1, c4, 0, 0, 0);
            c4 = __builtin_amdgcn_mfma_f32_16x16x32_bf16(ql0, kh0, c4, 0, 0, 0);
            c4 = __builtin_amdgcn_mfma_f32_16x16x32_bf16(ql1, kh1, c4, 0, 0, 0);
            int ci = iter * 128 + s * 16 + li;
            #pragma unroll
            for (int r = 0; r < 4; ++r) {
                float cv = c4[r] * SCALE;
                if (cv > tv[r][7]) insert8(tv[r], tix[r], cv, ci);
            }
        }
    }

    float* mv = (float*)smA;
    int*   mi = (int*)(smA + 16384);
    for (int bb = 0; bb < 2; ++bb) {
        __syncthreads();
        if ((wv >> 1) == bb) {
            int rl0 = (wv & 1) * 16 + quad * 4;
            #pragma unroll
            for (int r = 0; r < 4; ++r) {
                int base = (rl0 + r) * 128 + li * 8;
                #pragma unroll
                for (int s = 0; s < 8; ++s) { mv[base + s] = tv[r][s]; mi[base + s] = tix[r][s]; }
            }
        }
        __syncthreads();
        if (t < 128) {
            int rr = t >> 2, p = t & 3;
            int base = rr * 128 + p * 32;
            merge4(&mv[base], &mi[base], &mv[base + 8], &mi[base + 8],
                   &mv[base + 16], &mi[base + 16], &mv[base + 24], &mi[base + 24],
                   s2v[rr][p], s2i[rr][p]);
        }
        __syncthreads();
        if (t < 32) {
            int rr = t;
            int pp[4] = {0, 0, 0, 0};
            #pragma unroll
            for (int s = 0; s < 12; ++s) {
                float bv = -INFINITY; int bi = 0x7fffffff; int bc = 0;
                #pragma unroll
                for (int l = 0; l < 4; ++l) {
                    if (pp[l] < 8) {
                        float hv = s2v[rr][l][pp[l]]; int hi2 = s2i[rr][l][pp[l]];
                        if (hv > bv || (hv == bv && hi2 < bi)) { bv = hv; bi = hi2; bc = l; }
                    }
                }
                pp[bc] += 1;
                cidx[rr][s] = bi;
            }
        }
        __syncthreads();
        for (int task = t; task < 384; task += 256) {
            int row = task / 12, c = task - row * 12;
            const float* qp = q + ((size_t)(b * LL + qt * 64 + bb * 32 + row)) * DD + h * 64;
            const float* kp = k + ((size_t)(b * LL + cidx[row][c])) * DD + h * 64;
            float acc = 0.f;
            for (int d4 = 0; d4 < 16; ++d4) {
                f32x4 qa = *(const f32x4*)(qp + d4 * 4);
                f32x4 ka = *(const f32x4*)(kp + d4 * 4);
                acc = fmaf(qa[0], ka[0], acc);
                acc = fmaf(qa[1], ka[1], acc);
                acc = fmaf(qa[2], ka[2], acc);
                acc = fmaf(qa[3], ka[3], acc);
            }
            cs[row][c] = acc * SCALE;
        }
        __syncthreads();
        if (t < 32) {
            int rr = t;
            float vv[12]; int ii[12];
            #pragma unroll
            for (int c = 0; c < 12; ++c) { vv[c] = cs[rr][c]; ii[c] = cidx[rr][c]; }
            float fv[8]; int fi[8];
            #pragma unroll
            for (int s = 0; s < 8; ++s) {
                float bv = -INFINITY; int bi = 0x7fffffff; int bc = 0;
                #pragma unroll
                for (int c = 0; c < 12; ++c) {
                    if (vv[c] > bv || (vv[c] == bv && ii[c] < bi)) { bv = vv[c]; bi = ii[c]; bc = c; }
                }
                vv[bc] = -INFINITY;
                fv[s] = bv; fi[s] = bi;
            }
            float m = fv[0];
            float e0[8]; float sum = 0.f;
            #pragma unroll
            for (int s = 0; s < 8; ++s) { e0[s] = __expf(fv[s] - m); sum += e0[s]; }
            float inv = 1.0f / sum;
            int grow = bb * 32 + rr;
            float* awrow = aw + (((size_t)(b * HH + h) * LL) + (size_t)qt * 64 + grow) * LL;
            #pragma unroll
            for (int s = 0; s < 8; ++s) {
                float w8 = e0[s] * inv;
                awrow[fi[s]] = w8;
                wrow[grow][s] = w8; wix[grow][s] = fi[s];
            }
        }
    }
    __syncthreads();

    const float* vbase = v + ((size_t)b * LL) * DD + h * 64;
    #pragma unroll
    for (int i = 0; i < 4; ++i) {
        int id = i * 256 + t;
        int row = id >> 4, seg = id & 15;
        f32x4 acc = {0.f, 0.f, 0.f, 0.f};
        #pragma unroll
        for (int s = 0; s < 8; ++s) {
            float ws = wrow[row][s];
            f32x4 vvv = *(const f32x4*)(vbase + (size_t)wix[row][s] * DD + seg * 4);
            acc[0] = fmaf(ws, vvv[0], acc[0]);
            acc[1] = fmaf(ws, vvv[1], acc[1]);
            acc[2] = fmaf(ws, vvv[2], acc[2]);
            acc[3] = fmaf(ws, vvv[3], acc[3]);
        }
        *(f32x4*)(ctx + ((size_t)(b * LL + qt * 64 + row)) * DD + h * 64 + seg * 4) = acc;
    }
}

__global__ __launch_bounds__(256) void linear_ws_kernel(
    const float* __restrict__ ctx, const float* __restrict__ w,
    const float* __restrict__ bias, float* __restrict__ out)
{
    const int bid  = blockIdx.x;
    const int nb   = bid & 15, mb = bid >> 4;
    const int t    = threadIdx.x;
    const int wv   = t >> 6;
    const int lane = t & 63;
    const int li   = lane & 15;
    const int quad = lane >> 4;

    __shared__ u16 bhi[8192], blo[8192];

    f32x4 acc0 = {0.f,0.f,0.f,0.f}, acc1 = {0.f,0.f,0.f,0.f},
          acc2 = {0.f,0.f,0.f,0.f}, acc3 = {0.f,0.f,0.f,0.f};
    const float* arow = ctx + (size_t)(mb * 64 + wv * 16 + li) * DD;

    for (int kc = 0; kc < 8; ++kc) {
        __syncthreads();
        #pragma unroll
        for (int j = 0; j < 4; ++j) {
            int f   = j * 256 + t;
            int col = f >> 4;
            int c   = (f >> 2) & 3;
            int qd  = f & 3;
            const float* src = w + (size_t)(nb * 64 + col) * DD + kc * 128 + c * 32 + qd * 8;
            float x[8];
            *(f32x4*)x       = *(const f32x4*)src;
            *(f32x4*)(x + 4) = *(const f32x4*)(src + 4);
            bf16x8 h8, l8;
            #pragma unroll
            for (int e = 0; e < 8; ++e) { short hh, ll; splitbf(x[e], hh, ll); h8[e] = hh; l8[e] = ll; }
            int off = (((col >> 4) * 4 + c) << 9) + (qd << 7) + ((col & 15) << 3);
            *(bf16x8*)&bhi[off] = h8;
            *(bf16x8*)&blo[off] = l8;
        }
        __syncthreads();

        bf16x8 ah[4], al[4];
        #pragma unroll
        for (int c = 0; c < 4; ++c) {
            float x[8];
            *(f32x4*)x       = *(const f32x4*)(arow + kc * 128 + c * 32 + quad * 8);
            *(f32x4*)(x + 4) = *(const f32x4*)(arow + kc * 128 + c * 32 + quad * 8 + 4);
            #pragma unroll
            for (int e = 0; e < 8; ++e) { short hh, ll; splitbf(x[e], hh, ll); ah[c][e] = hh; al[c][e] = ll; }
        }
        #pragma unroll
        for (int c = 0; c < 4; ++c) {
            bf16x8 bh0 = *(bf16x8*)&bhi[(( 0 + c) << 9) + (lane << 3)];
            bf16x8 bl0 = *(bf16x8*)&blo[(( 0 + c) << 9) + (lane << 3)];
            bf16x8 bh1 = *(bf16x8*)&bhi[(( 4 + c) << 9) + (lane << 3)];
            bf16x8 bl1 = *(bf16x8*)&blo[(( 4 + c) << 9) + (lane << 3)];
            bf16x8 bh2 = *(bf16x8*)&bhi[(( 8 + c) << 9) + (lane << 3)];
            bf16x8 bl2 = *(bf16x8*)&blo[(( 8 + c) << 9) + (lane << 3)];
            bf16x8 bh3 = *(bf16x8*)&bhi[((12 + c) << 9) + (lane << 3)];
            bf16x8 bl3 = *(bf16x8*)&blo[((12 + c) << 9) + (lane << 3)];
            acc0 = __builtin_amdgcn_mfma_f32_16x16x32_bf16(ah[c], bh0, acc0, 0, 0, 0);
            acc0 = __builtin_amdgcn_mfma_f32_16x16x32_bf16(ah[c], bl0, acc0, 0, 0, 0);
            acc0 = __builtin_amdgcn_mfma_f32_16x16x32_bf16(al[c], bh0, acc0, 0, 0, 0);
            acc1 = __builtin_amdgcn_mfma_f32_16x16x32_bf16(ah[c], bh1, acc1, 0, 0, 0);
            acc1 = __builtin_amdgcn_mfma_f32_16x16x32_bf16(ah[c], bl1, acc1, 0, 0, 0);
            acc1 = __builtin_amdgcn_mfma_f32_16x16x32_bf16(al[c], bh1, acc1, 0, 0, 0);
            acc2 = __builtin_amdgcn_mfma_f32_16x16x32_bf16(ah[c], bh2, acc2, 0, 0, 0);
            acc2 = __builtin_amdgcn_mfma_f32_16x16x32_bf16(ah[c], bl2, acc2, 0, 0, 0);
            acc2 = __builtin_amdgcn_mfma_f32_16x16x32_bf16(al[c], bh2, acc2, 0, 0, 0);
            acc3 = __builtin_amdgcn_mfma_f32_16x16x32_bf16(ah[c], bh3, acc3, 0, 0, 0);
            acc3 = __builtin_amdgcn_mfma_f32_16x16x32_bf16(ah[c], bl3, acc3, 0, 0, 0);
            acc3 = __builtin_amdgcn_mfma_f32_16x16x32_bf16(al[c], bh3, acc3, 0, 0, 0);
        }
    }

    #pragma unroll
    for (int st = 0; st < 4; ++st) {
        f32x4 a = (st == 0) ? acc0 : (st == 1) ? acc1 : (st == 2) ? acc2 : acc3;
        int col = nb * 64 + st * 16 + li;
        float bb2 = bias[col];
        #pragma unroll
        for (int r = 0; r < 4; ++r)
            out[(size_t)(mb * 64 + wv * 16 + quad * 4 + r) * DD + col] = a[r] + bb2;
    }
}

__global__ __launch_bounds__(256) void linear_inplace_kernel(
    float* io, const float* __restrict__ w, const float* __restrict__ bias)
{
    __shared__ u16 ahi[16384], alo[16384];
    const int t    = threadIdx.x;
    const int m0   = blockIdx.x * 16;
    const int wv   = t >> 6;
    const int lane = t & 63;
    const int li   = lane & 15;
    const int quad = lane >> 4;

    #pragma unroll
    for (int i = 0; i < 8; ++i) {
        int id  = i * 256 + t;
        int row = id >> 7;
        int c   = (id >> 2) & 31;
        int qd  = id & 3;
        const float* src = io + (size_t)(m0 + row) * DD + c * 32 + qd * 8;
        float x[8];
        *(f32x4*)x       = *(const f32x4*)src;
        *(f32x4*)(x + 4) = *(const f32x4*)(src + 4);
        bf16x8 h8, l8;
        #pragma unroll
        for (int e = 0; e < 8; ++e) { short hh, ll; splitbf(x[e], hh, ll); h8[e] = hh; l8[e] = ll; }
        int off = (c << 9) + (qd << 7) + (row << 3);
        *(bf16x8*)&ahi[off] = h8;
        *(bf16x8*)&alo[off] = l8;
    }
    __syncthreads();

    f32x4 acc[16];
    #pragma unroll
    for (int i = 0; i < 16; ++i) acc[i] = (f32x4){0.f, 0.f, 0.f, 0.f};

    for (int c = 0; c < 32; ++c) {
        bf16x8 ah = *(bf16x8*)&ahi[(c << 9) + (lane << 3)];
        bf16x8 al = *(bf16x8*)&alo[(c << 9) + (lane << 3)];
        #pragma unroll
        for (int sub = 0; sub < 16; ++sub) {
            int col = wv * 256 + sub * 16 + li;
            const float* src = w + (size_t)col * DD + c * 32 + quad * 8;
            float x[8];
            *(f32x4*)x       = *(const f32x4*)src;
            *(f32x4*)(x + 4) = *(const f32x4*)(src + 4);
            bf16x8 bh, bl;
            #pragma unroll
            for (int e = 0; e < 8; ++e) { short hh, ll; splitbf(x[e], hh, ll); bh[e] = hh; bl[e] = ll; }
            acc[sub] = __builtin_amdgcn_mfma_f32_16x16x32_bf16(ah, bh, acc[sub], 0, 0, 0);
            acc[sub] = __builtin_amdgcn_mfma_f32_16x16x32_bf16(ah, bl, acc[sub], 0, 0, 0);
            acc[sub] = __builtin_amdgcn_mfma_f32_16x16x32_bf16(al, bh, acc[sub], 0, 0, 0);
        }
    }

    #pragma unroll
    for (int sub = 0; sub < 16; ++sub) {
        int col = wv * 256 + sub * 16 + li;
        float bb2 = bias[col];
        #pragma unroll
        for (int r = 0; r < 4; ++r)
            io[(size_t)(m0 + quad * 4 + r) * DD + col] = acc[sub][r] + bb2;
    }
}

extern "C" void kernel_launch(void* const* d_in, const int* in_sizes, int n_in,
                              void* d_out, int out_size, void* d_ws, size_t ws_size,
                              hipStream_t stream) {
    const float* q    = (const float*)d_in[0];
    const float* k    = (const float*)d_in[1];
    const float* v    = (const float*)d_in[2];
    const float* w    = (const float*)d_in[3];
    const float* bias = (const float*)d_in[4];

    float* out = (float*)d_out;                  // attn_out [B*L*D]
    float* aw  = out + ATTN_ELEMS;               // attn_weights [B*H*L*L]

    const size_t CHI_ELE = ATTN_ELEMS;           // shorts (ctx split)
    const size_t KSP_ELE = 4194304;              // shorts (k split, fragment layout)
    const size_t WSP_ELE = 1048576;              // shorts (w split, fragment layout)
    const size_t need_fast = (2 * CHI_ELE + 2 * KSP_ELE + 2 * WSP_ELE) * sizeof(u16); // 36 MB

    if (d_ws != nullptr && ws_size >= need_fast) {
        u16* chi = (u16*)d_ws;
        u16* clo = chi + CHI_ELE;
        u16* khi = clo + CHI_ELE;
        u16* klo = khi + KSP_ELE;
        u16* whi = klo + KSP_ELE;
        u16* wlo = whi + WSP_ELE;
        prep_k_kernel<<<2048, 256, 0, stream>>>(k, khi, klo);
        prep_w_kernel<<<512, 256, 0, stream>>>(w, whi, wlo);
        attn_fast_kernel<<<BB * HH * (LL / 64), 256, 0, stream>>>(q, k, v, khi, klo, aw, chi, clo);
        linear_fast_kernel<<<(BB * LL / 64) * (DD / 64), 256, 0, stream>>>(chi, clo, whi, wlo, bias, out);
    } else {
        const bool use_ws = (d_ws != nullptr) && (ws_size >= ATTN_ELEMS * sizeof(float));
        float* ctx = use_ws ? (float*)d_ws : out;
        attn_kernel<<<BB * HH * (LL / 64), 256, 0, stream>>>(q, k, v, aw, ctx);
        if (use_ws) {
            linear_ws_kernel<<<(BB * LL / 64) * (DD / 64), 256, 0, stream>>>(ctx, w, bias, out);
        } else {
            linear_inplace_kernel<<<BB * LL / 16, 256, 0, stream>>>(out, w, bias);
        }
    }
}

// Round 5
// 910.348 us; speedup vs baseline: 1.2005x; 1.2005x over previous
//
#include <hip/hip_runtime.h>
#include <math.h>

#define BB 2
#define LL 2048
#define DD 1024
#define HH 16
#define SCALE 0.03125f   // 1/sqrt(1024)

#define ATTN_ELEMS ((size_t)BB * LL * DD)           // 4,194,304 fp32

typedef unsigned short u16;
typedef __attribute__((ext_vector_type(8))) short bf16x8;
typedef __attribute__((ext_vector_type(4))) short s16x4;
typedef __attribute__((ext_vector_type(4))) float f32x4;

__device__ __forceinline__ u16 f2bf_rne(float f) {
    union { float f; unsigned u; } c; c.f = f;
    unsigned u = c.u;
    u += 0x7fffu + ((u >> 16) & 1u);
    return (u16)(u >> 16);
}

// fp32 -> bf16 hi (truncate) + bf16 lo (RNE of residual); x ≈ hi+lo, |err| ≲ 2^-17|x|
__device__ __forceinline__ void splitbf(float x, short& h, short& l) {
    union { float f; unsigned u; } c; c.f = x;
    unsigned uh = c.u & 0xFFFF0000u;
    h = (short)(uh >> 16);
    union { unsigned u; float f; } ch; ch.u = uh;
    l = (short)f2bf_rne(x - ch.f);
}

// Branchless stable insert of (cv,ci) into descending-sorted 8-list.
// Precondition: cv > tv[7]. Candidates arrive in ascending index order.
__device__ __forceinline__ void insert8(float (&tv)[8], int (&ti)[8], float cv, int ci) {
    bool g0 = cv > tv[0], g1 = cv > tv[1], g2 = cv > tv[2], g3 = cv > tv[3],
         g4 = cv > tv[4], g5 = cv > tv[5], g6 = cv > tv[6];
    tv[7] = g6 ? tv[6] : cv;                 ti[7] = g6 ? ti[6] : ci;
    tv[6] = g5 ? tv[5] : (g6 ? cv : tv[6]);  ti[6] = g5 ? ti[5] : (g6 ? ci : ti[6]);
    tv[5] = g4 ? tv[4] : (g5 ? cv : tv[5]);  ti[5] = g4 ? ti[4] : (g5 ? ci : ti[5]);
    tv[4] = g3 ? tv[3] : (g4 ? cv : tv[4]);  ti[4] = g3 ? ti[3] : (g4 ? ci : ti[4]);
    tv[3] = g2 ? tv[2] : (g3 ? cv : tv[3]);  ti[3] = g2 ? ti[2] : (g3 ? ci : ti[3]);
    tv[2] = g1 ? tv[1] : (g2 ? cv : tv[2]);  ti[2] = g1 ? ti[1] : (g2 ? ci : ti[2]);
    tv[1] = g0 ? tv[0] : (g1 ? cv : tv[1]);  ti[1] = g0 ? ti[0] : (g1 ? ci : ti[1]);
    tv[0] = g0 ? cv : tv[0];                 ti[0] = g0 ? ci : ti[0];
}

// Tie-aware variant: composite order (value desc, index asc).
// Precondition: (cv,ci) outranks slot 7.
__device__ __forceinline__ void insert8t(float (&tv)[8], int (&ti)[8], float cv, int ci) {
    bool g0 = cv > tv[0] || (cv == tv[0] && ci < ti[0]);
    bool g1 = cv > tv[1] || (cv == tv[1] && ci < ti[1]);
    bool g2 = cv > tv[2] || (cv == tv[2] && ci < ti[2]);
    bool g3 = cv > tv[3] || (cv == tv[3] && ci < ti[3]);
    bool g4 = cv > tv[4] || (cv == tv[4] && ci < ti[4]);
    bool g5 = cv > tv[5] || (cv == tv[5] && ci < ti[5]);
    bool g6 = cv > tv[6] || (cv == tv[6] && ci < ti[6]);
    tv[7] = g6 ? tv[6] : cv;                 ti[7] = g6 ? ti[6] : ci;
    tv[6] = g5 ? tv[5] : (g6 ? cv : tv[6]);  ti[6] = g5 ? ti[5] : (g6 ? ci : ti[6]);
    tv[5] = g4 ? tv[4] : (g5 ? cv : tv[5]);  ti[5] = g4 ? ti[4] : (g5 ? ci : ti[5]);
    tv[4] = g3 ? tv[3] : (g4 ? cv : tv[4]);  ti[4] = g3 ? ti[3] : (g4 ? ci : ti[4]);
    tv[3] = g2 ? tv[2] : (g3 ? cv : tv[3]);  ti[3] = g2 ? ti[2] : (g3 ? ci : ti[3]);
    tv[2] = g1 ? tv[1] : (g2 ? cv : tv[2]);  ti[2] = g1 ? ti[1] : (g2 ? ci : ti[2]);
    tv[1] = g0 ? tv[0] : (g1 ? cv : tv[1]);  ti[1] = g0 ? ti[0] : (g1 ? ci : ti[1]);
    tv[0] = g0 ? cv : tv[0];                 ti[0] = g0 ? ci : ti[0];
}

// Branchless stable insert into descending-sorted 12-list (precondition cv > tv[11]).
__device__ __forceinline__ void insert12(float (&tv)[12], int (&ti)[12], float cv, int ci) {
    bool g0 = cv > tv[0], g1 = cv > tv[1], g2 = cv > tv[2], g3 = cv > tv[3],
         g4 = cv > tv[4], g5 = cv > tv[5], g6 = cv > tv[6], g7 = cv > tv[7],
         g8 = cv > tv[8], g9 = cv > tv[9], g10 = cv > tv[10];
    tv[11] = g10 ? tv[10] : cv;                 ti[11] = g10 ? ti[10] : ci;
    tv[10] = g9 ? tv[9] : (g10 ? cv : tv[10]);  ti[10] = g9 ? ti[9] : (g10 ? ci : ti[10]);
    tv[9]  = g8 ? tv[8] : (g9 ? cv : tv[9]);    ti[9]  = g8 ? ti[8] : (g9 ? ci : ti[9]);
    tv[8]  = g7 ? tv[7] : (g8 ? cv : tv[8]);    ti[8]  = g7 ? ti[7] : (g8 ? ci : ti[8]);
    tv[7]  = g6 ? tv[6] : (g7 ? cv : tv[7]);    ti[7]  = g6 ? ti[6] : (g7 ? ci : ti[7]);
    tv[6]  = g5 ? tv[5] : (g6 ? cv : tv[6]);    ti[6]  = g5 ? ti[5] : (g6 ? ci : ti[6]);
    tv[5]  = g4 ? tv[4] : (g5 ? cv : tv[5]);    ti[5]  = g4 ? ti[4] : (g5 ? ci : ti[5]);
    tv[4]  = g3 ? tv[3] : (g4 ? cv : tv[4]);    ti[4]  = g3 ? ti[3] : (g4 ? ci : ti[4]);
    tv[3]  = g2 ? tv[2] : (g3 ? cv : tv[3]);    ti[3]  = g2 ? ti[2] : (g3 ? ci : ti[3]);
    tv[2]  = g1 ? tv[1] : (g2 ? cv : tv[2]);    ti[2]  = g1 ? ti[1] : (g2 ? ci : ti[2]);
    tv[1]  = g0 ? tv[0] : (g1 ? cv : tv[1]);    ti[1]  = g0 ? ti[0] : (g1 ? ci : ti[1]);
    tv[0]  = g0 ? cv : tv[0];                   ti[0]  = g0 ? ci : ti[0];
}

// Merge four descending-sorted 8-lists -> top-8 (value desc, index asc on ties).
__device__ __forceinline__ void merge4(
    const float* v0, const int* i0, const float* v1, const int* i1,
    const float* v2, const int* i2, const float* v3, const int* i3,
    float* ov, int* oi)
{
    int p0 = 0, p1 = 0, p2 = 0, p3 = 0;
    #pragma unroll
    for (int s = 0; s < 8; ++s) {
        float a0 = v0[p0], a1 = v1[p1], a2 = v2[p2], a3 = v3[p3];
        int   b0 = i0[p0], b1 = i1[p1], b2 = i2[p2], b3 = i3[p3];
        float bv = a0; int bi = b0; int bc = 0;
        if (a1 > bv || (a1 == bv && b1 < bi)) { bv = a1; bi = b1; bc = 1; }
        if (a2 > bv || (a2 == bv && b2 < bi)) { bv = a2; bi = b2; bc = 2; }
        if (a3 > bv || (a3 == bv && b3 < bi)) { bv = a3; bi = b3; bc = 3; }
        p0 += (bc == 0); p1 += (bc == 1); p2 += (bc == 2); p3 += (bc == 3);
        ov[s] = bv; oi[s] = bi;
    }
}

// ===========================================================================
// FAST PATH (ws >= 36 MB)
// ===========================================================================

// K fp32 -> split-bf16, stored in MFMA fragment layout per (b,h):
// shorts offset within head = s*1024 + c*512 + qd*128 + li*8  (head stride 131072)
__global__ __launch_bounds__(256) void prep_k_kernel(
    const float* __restrict__ k, u16* __restrict__ khi, u16* __restrict__ klo)
{
    int gid = blockIdx.x * 256 + threadIdx.x;          // 0 .. 524287
    int li   = gid & 15;
    int qd   = (gid >> 4) & 3;
    int c    = (gid >> 6) & 1;
    int s    = (gid >> 7) & 127;
    int head = gid >> 14;                              // 0 .. 31
    int b = head >> 4, h = head & 15;
    const float* src = k + ((size_t)(b * LL + s * 16 + li)) * DD + h * 64 + c * 32 + qd * 8;
    float x[8];
    *(f32x4*)x       = *(const f32x4*)src;
    *(f32x4*)(x + 4) = *(const f32x4*)(src + 4);
    bf16x8 h8, l8;
    #pragma unroll
    for (int e = 0; e < 8; ++e) { short hh, ll; splitbf(x[e], hh, ll); h8[e] = hh; l8[e] = ll; }
    *(bf16x8*)&khi[(size_t)gid * 8] = h8;
    *(bf16x8*)&klo[(size_t)gid * 8] = l8;
}

// W fp32 -> split-bf16 fragment layout:
// shorts offset = nb*65536 + kc*8192 + nt*2048 + c*512 + qd*128 + li*8
__global__ __launch_bounds__(256) void prep_w_kernel(
    const float* __restrict__ w, u16* __restrict__ whi, u16* __restrict__ wlo)
{
    int gid = blockIdx.x * 256 + threadIdx.x;          // 0 .. 131071
    int li = gid & 15;
    int qd = (gid >> 4) & 3;
    int c  = (gid >> 6) & 3;
    int nt = (gid >> 8) & 3;
    int kc = (gid >> 10) & 7;
    int nb = gid >> 13;                                // 0 .. 15
    const float* src = w + (size_t)(nb * 64 + nt * 16 + li) * DD + kc * 128 + c * 32 + qd * 8;
    float x[8];
    *(f32x4*)x       = *(const f32x4*)src;
    *(f32x4*)(x + 4) = *(const f32x4*)(src + 4);
    bf16x8 h8, l8;
    #pragma unroll
    for (int e = 0; e < 8; ++e) { short hh, ll; splitbf(x[e], hh, ll); h8[e] = hh; l8[e] = ll; }
    *(bf16x8*)&whi[(size_t)gid * 8] = h8;
    *(bf16x8*)&wlo[(size_t)gid * 8] = l8;
}

// Fused attention, fast path v5: group-max scan with 2-phase LDS double-buffer.
// Tile = 4 K-steps (16 KB). Wave wv stages step wv via reg-staging (T14: issue
// loads early, ds_write after compute). All 4 waves share one K stream through
// LDS (4x less global traffic; one vmcnt drain per tile instead of per pair).
// kbuf (32 KB) is overlaid by the merge arena after the scan. Numerics
// bit-identical to the passing v3/v4 (same MFMA sequence, same selection).
__global__ __launch_bounds__(256) void attn_fast_kernel(
    const float* __restrict__ q, const float* __restrict__ k, const float* __restrict__ v,
    const u16* __restrict__ khi_g, const u16* __restrict__ klo_g,
    float* __restrict__ aw, u16* __restrict__ chi, u16* __restrict__ clo)
{
    // bijective XCD swizzle: blocks of one head cluster on one XCD.
    const int swz  = (blockIdx.x & 7) * 128 + (blockIdx.x >> 3);
    const int qt   = swz & 31;
    const int h    = (swz >> 5) & 15;
    const int b    = swz >> 9;
    const int t    = threadIdx.x;
    const int wv   = t >> 6;
    const int lane = t & 63;
    const int li   = lane & 15;
    const int quad = lane >> 4;

    // 32 KB shared arena.
    // SCAN phase: kbuf double buffer, 2 x 4 steps x 4 KB (step = 4 frags x 1 KB,
    //   frag layout lane*16 B: [kh0 @0, kh1 @1 KB, kl0 @2 KB, kl1 @3 KB]).
    // POST-SCAN overlays (same offsets as v4):
    //  [0,1536)      gsel u16[64][12]
    //  [1536,13824)  dv f32[64][48]  -> s2v f32[256][9] @1536
    //  [13824,19968) dg u16[64][48]  -> s2i u16[256][9] @13824
    //  [18432,20480) wrow f32[64][8]
    //  [20480,21504) wix u16[64][8]
    __shared__ __align__(16) char smem[32768];
    u16*   kb0  = (u16*)(smem);
    u16*   kb1  = (u16*)(smem + 16384);
    u16*   gsel = (u16*)(smem);
    float* dv   = (float*)(smem + 1536);
    u16*   dg   = (u16*)(smem + 13824);
    float* s2v  = (float*)(smem + 1536);
    u16*   s2i  = (u16*)(smem + 13824);
    float* wrow = (float*)(smem + 18432);
    u16*   wixs = (u16*)(smem + 20480);

    f32x4* awz = (f32x4*)(aw + (((size_t)(b * HH + h) * LL) + (size_t)qt * 64) * LL);
    const f32x4 zero4 = {0.f, 0.f, 0.f, 0.f};

    // Q fragments (split-bf16). Lane data = Q[row wv*16+li][dims quad*8..] = B-operand col li.
    bf16x8 qh0, ql0, qh1, ql1;
    {
        const float* qrow = q + ((size_t)(b * LL + qt * 64 + wv * 16 + li)) * DD + h * 64;
        float x[8];
        *(f32x4*)x       = *(const f32x4*)(qrow + quad * 8);
        *(f32x4*)(x + 4) = *(const f32x4*)(qrow + quad * 8 + 4);
        #pragma unroll
        for (int e = 0; e < 8; ++e) { short hh, ll; splitbf(x[e], hh, ll); qh0[e] = hh; ql0[e] = ll; }
        *(f32x4*)x       = *(const f32x4*)(qrow + 32 + quad * 8);
        *(f32x4*)(x + 4) = *(const f32x4*)(qrow + 32 + quad * 8 + 4);
        #pragma unroll
        for (int e = 0; e < 8; ++e) { short hh, ll; splitbf(x[e], hh, ll); qh1[e] = hh; ql1[e] = ll; }
    }

    // Per-lane top-12 GROUPS for q-row (wv*16 + li). Group key gk = sp*32 + quad*4;
    // its 8 candidates are k = gk + (e>>2)*16 + (e&3), e=0..7.
    float tv[12]; int tg[12];
    #pragma unroll
    for (int s = 0; s < 12; ++s) { tv[s] = -INFINITY; tg[s] = 0; }

    const u16* khb = khi_g + (size_t)(b * HH + h) * 131072 + (size_t)lane * 8;
    const u16* klb = klo_g + (size_t)(b * HH + h) * 131072 + (size_t)lane * 8;

    // ---- prologue: stage tile 0 (wave wv stages step wv) ----
    {
        const size_t g = (size_t)wv * 1024;
        bf16x8 r0 = *(const bf16x8*)(khb + g);
        bf16x8 r1 = *(const bf16x8*)(khb + g + 512);
        bf16x8 r2 = *(const bf16x8*)(klb + g);
        bf16x8 r3 = *(const bf16x8*)(klb + g + 512);
        u16* dst = kb0 + wv * 2048 + lane * 8;
        *(bf16x8*)(dst)        = r0;
        *(bf16x8*)(dst + 512)  = r1;
        *(bf16x8*)(dst + 1024) = r2;
        *(bf16x8*)(dst + 1536) = r3;
    }
    __syncthreads();

    int cur = 0;
    for (int tile = 0; tile < 32; ++tile) {
        // issue next tile's loads (wave wv -> step wv of tile+1)
        bf16x8 r0, r1, r2, r3;
        const bool pf = (tile < 31);
        if (pf) {
            const size_t g = ((size_t)(tile + 1) * 4 + wv) * 1024;
            r0 = *(const bf16x8*)(khb + g);
            r1 = *(const bf16x8*)(khb + g + 512);
            r2 = *(const bf16x8*)(klb + g);
            r3 = *(const bf16x8*)(klb + g + 512);
        }
        // zero-fill rides along (4 f32x4 per thread per tile)
        #pragma unroll
        for (int z = 0; z < 4; ++z) awz[tile * 1024 + z * 256 + t] = zero4;

        // compute two step-pairs from the current buffer
        const u16* base = cur ? kb1 : kb0;
        #pragma unroll
        for (int p = 0; p < 2; ++p) {
            const int soA = (2 * p) * 2048 + lane * 8;
            const int soB = (2 * p + 1) * 2048 + lane * 8;
            bf16x8 Ah0 = *(const bf16x8*)(base + soA);
            bf16x8 Ah1 = *(const bf16x8*)(base + soA + 512);
            bf16x8 Al0 = *(const bf16x8*)(base + soA + 1024);
            bf16x8 Al1 = *(const bf16x8*)(base + soA + 1536);
            bf16x8 Bh0 = *(const bf16x8*)(base + soB);
            bf16x8 Bh1 = *(const bf16x8*)(base + soB + 512);
            bf16x8 Bl0 = *(const bf16x8*)(base + soB + 1024);
            bf16x8 Bl1 = *(const bf16x8*)(base + soB + 1536);

            f32x4 c4a = {0,0,0,0}, c4b = {0,0,0,0}, d4a = {0,0,0,0}, d4b = {0,0,0,0};
            c4a = __builtin_amdgcn_mfma_f32_16x16x32_bf16(Ah0, qh0, c4a, 0, 0, 0);
            c4b = __builtin_amdgcn_mfma_f32_16x16x32_bf16(Ah1, qh1, c4b, 0, 0, 0);
            d4a = __builtin_amdgcn_mfma_f32_16x16x32_bf16(Bh0, qh0, d4a, 0, 0, 0);
            d4b = __builtin_amdgcn_mfma_f32_16x16x32_bf16(Bh1, qh1, d4b, 0, 0, 0);
            c4a = __builtin_amdgcn_mfma_f32_16x16x32_bf16(Al0, qh0, c4a, 0, 0, 0);
            c4b = __builtin_amdgcn_mfma_f32_16x16x32_bf16(Al1, qh1, c4b, 0, 0, 0);
            d4a = __builtin_amdgcn_mfma_f32_16x16x32_bf16(Bl0, qh0, d4a, 0, 0, 0);
            d4b = __builtin_amdgcn_mfma_f32_16x16x32_bf16(Bl1, qh1, d4b, 0, 0, 0);
            c4a = __builtin_amdgcn_mfma_f32_16x16x32_bf16(Ah0, ql0, c4a, 0, 0, 0);
            c4b = __builtin_amdgcn_mfma_f32_16x16x32_bf16(Ah1, ql1, c4b, 0, 0, 0);
            d4a = __builtin_amdgcn_mfma_f32_16x16x32_bf16(Bh0, ql0, d4a, 0, 0, 0);
            d4b = __builtin_amdgcn_mfma_f32_16x16x32_bf16(Bh1, ql1, d4b, 0, 0, 0);

            float s0 = c4a[0] + c4b[0], s1 = c4a[1] + c4b[1];
            float s2 = c4a[2] + c4b[2], s3 = c4a[3] + c4b[3];
            float s4 = d4a[0] + d4b[0], s5 = d4a[1] + d4b[1];
            float s6 = d4a[2] + d4b[2], s7 = d4a[3] + d4b[3];
            float m = fmaxf(fmaxf(fmaxf(s0, s1), fmaxf(s2, s3)),
                            fmaxf(fmaxf(s4, s5), fmaxf(s6, s7)));
            const int sp = tile * 2 + p;
            if (m > tv[11]) insert12(tv, tg, m, sp * 32 + quad * 4);
        }

        // write staged regs into the other buffer (vmcnt wait lands here,
        // after the compute phase hid the load latency)
        if (pf) {
            u16* dst = (cur ? kb0 : kb1) + wv * 2048 + lane * 8;
            *(bf16x8*)(dst)        = r0;
            *(bf16x8*)(dst + 512)  = r1;
            *(bf16x8*)(dst + 1024) = r2;
            *(bf16x8*)(dst + 1536) = r3;
        }
        __syncthreads();
        cur ^= 1;
    }

    // ---- P0 dump per-lane sorted group lists (kbuf dead; arena overlays) ----
    {
        const int row = wv * 16 + li;
        #pragma unroll
        for (int s = 0; s < 12; ++s) {
            dv[row * 48 + quad * 12 + s] = tv[s];
            dg[row * 48 + quad * 12 + s] = (u16)tg[s];
        }
    }
    __syncthreads();

    // ---- P1: merge 4 sorted 12-lists -> top-12 groups per row ----
    if (t < 64) {
        const float* v0 = &dv[t * 48];       const u16* i0 = &dg[t * 48];
        const float* v1 = &dv[t * 48 + 12];  const u16* i1 = &dg[t * 48 + 12];
        const float* v2 = &dv[t * 48 + 24];  const u16* i2 = &dg[t * 48 + 24];
        const float* v3 = &dv[t * 48 + 36];  const u16* i3 = &dg[t * 48 + 36];
        int p0 = 0, p1 = 0, p2 = 0, p3 = 0;
        #pragma unroll
        for (int s = 0; s < 12; ++s) {
            float a0 = v0[p0], a1 = v1[p1], a2 = v2[p2], a3 = v3[p3];
            int   b0 = i0[p0], b1 = i1[p1], b2 = i2[p2], b3 = i3[p3];
            float bv = a0; int bi = b0; int bc = 0;
            if (a1 > bv || (a1 == bv && b1 < bi)) { bv = a1; bi = b1; bc = 1; }
            if (a2 > bv || (a2 == bv && b2 < bi)) { bv = a2; bi = b2; bc = 2; }
            if (a3 > bv || (a3 == bv && b3 < bi)) { bv = a3; bi = b3; bc = 3; }
            p0 += (bc == 0); p1 += (bc == 1); p2 += (bc == 2); p3 += (bc == 3);
            gsel[t * 12 + s] = (u16)bi;
        }
    }
    __syncthreads();

    // ---- P3: exact rescore of 96 candidates/row, paired for ILP ----
    {
        const int row = t >> 2, p = t & 3;
        const float* qp = q + ((size_t)(b * LL + qt * 64 + row)) * DD + h * 64;
        f32x4 qr[16];
        #pragma unroll
        for (int d4 = 0; d4 < 16; ++d4) qr[d4] = *(const f32x4*)(qp + d4 * 4);
        float tv8[8]; int ti8[8];
        #pragma unroll
        for (int s = 0; s < 8; ++s) { tv8[s] = -INFINITY; ti8[s] = 0x7fffffff; }
        for (int jj = 0; jj < 24; jj += 2) {
            // j = p*24 + jj; p*24 % 8 == 0 so group index = p*3 + jj/8, e = jj&7.
            int gk = (int)gsel[row * 12 + p * 3 + (jj >> 3)];
            int e  = jj & 7;
            int k0 = gk + ((e >> 2) << 4) + (e & 3);   // e even -> pair is k0, k0+1
            int k1 = k0 + 1;
            const float* kp0 = k + ((size_t)(b * LL + k0)) * DD + h * 64;
            const float* kp1 = k + ((size_t)(b * LL + k1)) * DD + h * 64;
            float a0 = 0.f, a1 = 0.f, a2 = 0.f, a3 = 0.f;
            float b0 = 0.f, b1 = 0.f, b2 = 0.f, b3 = 0.f;
            #pragma unroll
            for (int d4 = 0; d4 < 16; ++d4) {
                f32x4 ka = *(const f32x4*)(kp0 + d4 * 4);
                f32x4 kb = *(const f32x4*)(kp1 + d4 * 4);
                a0 = fmaf(qr[d4][0], ka[0], a0);
                a1 = fmaf(qr[d4][1], ka[1], a1);
                a2 = fmaf(qr[d4][2], ka[2], a2);
                a3 = fmaf(qr[d4][3], ka[3], a3);
                b0 = fmaf(qr[d4][0], kb[0], b0);
                b1 = fmaf(qr[d4][1], kb[1], b1);
                b2 = fmaf(qr[d4][2], kb[2], b2);
                b3 = fmaf(qr[d4][3], kb[3], b3);
            }
            float sc0 = ((a0 + a1) + (a2 + a3)) * SCALE;
            float sc1 = ((b0 + b1) + (b2 + b3)) * SCALE;
            if (sc0 > tv8[7] || (sc0 == tv8[7] && k0 < ti8[7])) insert8t(tv8, ti8, sc0, k0);
            if (sc1 > tv8[7] || (sc1 == tv8[7] && k1 < ti8[7])) insert8t(tv8, ti8, sc1, k1);
        }
        #pragma unroll
        for (int s = 0; s < 8; ++s) {
            s2v[(row * 4 + p) * 9 + s] = tv8[s];
            s2i[(row * 4 + p) * 9 + s] = (u16)ti8[s];
        }
    }
    __syncthreads();

    // ---- P4: merge 4 top-8 lists -> exact top-8, softmax, scatter ----
    if (t < 64) {
        const float* v0 = &s2v[(t * 4 + 0) * 9]; const u16* i0 = &s2i[(t * 4 + 0) * 9];
        const float* v1 = &s2v[(t * 4 + 1) * 9]; const u16* i1 = &s2i[(t * 4 + 1) * 9];
        const float* v2 = &s2v[(t * 4 + 2) * 9]; const u16* i2 = &s2i[(t * 4 + 2) * 9];
        const float* v3 = &s2v[(t * 4 + 3) * 9]; const u16* i3 = &s2i[(t * 4 + 3) * 9];
        int p0 = 0, p1 = 0, p2 = 0, p3 = 0;
        float fv[8]; int fi[8];
        #pragma unroll
        for (int s = 0; s < 8; ++s) {
            float a0 = v0[p0], a1 = v1[p1], a2 = v2[p2], a3 = v3[p3];
            int   b0 = i0[p0], b1 = i1[p1], b2 = i2[p2], b3 = i3[p3];
            float bv = a0; int bi = b0; int bc = 0;
            if (a1 > bv || (a1 == bv && b1 < bi)) { bv = a1; bi = b1; bc = 1; }
            if (a2 > bv || (a2 == bv && b2 < bi)) { bv = a2; bi = b2; bc = 2; }
            if (a3 > bv || (a3 == bv && b3 < bi)) { bv = a3; bi = b3; bc = 3; }
            p0 += (bc == 0); p1 += (bc == 1); p2 += (bc == 2); p3 += (bc == 3);
            fv[s] = bv; fi[s] = bi;
        }
        float m = fv[0];
        float e0[8]; float sum = 0.f;
        #pragma unroll
        for (int s = 0; s < 8; ++s) { e0[s] = __expf(fv[s] - m); sum += e0[s]; }
        float inv = 1.0f / sum;
        float* awrow = aw + (((size_t)(b * HH + h) * LL) + (size_t)qt * 64 + t) * LL;
        #pragma unroll
        for (int s = 0; s < 8; ++s) {
            float w8 = e0[s] * inv;
            awrow[fi[s]] = w8;
            wrow[t * 8 + s] = w8; wixs[t * 8 + s] = (u16)fi[s];
        }
    }
    __syncthreads();

    // ---- P5: context = P @ V; emit split-bf16 directly ----
    const float* vbase = v + ((size_t)b * LL) * DD + h * 64;
    #pragma unroll
    for (int i = 0; i < 4; ++i) {
        int id = i * 256 + t;
        int row = id >> 4, seg = id & 15;
        f32x4 acc = {0.f, 0.f, 0.f, 0.f};
        #pragma unroll
        for (int s = 0; s < 8; ++s) {
            float ws = wrow[row * 8 + s];
            f32x4 vvv = *(const f32x4*)(vbase + (size_t)wixs[row * 8 + s] * DD + seg * 4);
            acc[0] = fmaf(ws, vvv[0], acc[0]);
            acc[1] = fmaf(ws, vvv[1], acc[1]);
            acc[2] = fmaf(ws, vvv[2], acc[2]);
            acc[3] = fmaf(ws, vvv[3], acc[3]);
        }
        size_t off = ((size_t)(b * LL + qt * 64 + row)) * DD + h * 64 + seg * 4;
        s16x4 h4, l4;
        #pragma unroll
        for (int j = 0; j < 4; ++j) { short hh, ll; splitbf(acc[j], hh, ll); h4[j] = hh; l4[j] = ll; }
        *(s16x4*)(chi + off) = h4;
        *(s16x4*)(clo + off) = l4;
    }
}

// Projection, fast path: A (ctx) and B (w) both pre-split; pure load + MFMA.
__global__ __launch_bounds__(256) void linear_fast_kernel(
    const u16* __restrict__ chi, const u16* __restrict__ clo,
    const u16* __restrict__ whi, const u16* __restrict__ wlo,
    const float* __restrict__ bias, float* __restrict__ out)
{
    const int bid  = blockIdx.x;
    const int nb   = bid & 15, mb = bid >> 4;
    const int t    = threadIdx.x;
    const int wv   = t >> 6;
    const int lane = t & 63;
    const int li   = lane & 15;
    const int quad = lane >> 4;

    f32x4 acc0 = {0.f,0.f,0.f,0.f}, acc1 = {0.f,0.f,0.f,0.f},
          acc2 = {0.f,0.f,0.f,0.f}, acc3 = {0.f,0.f,0.f,0.f};

    const u16* ah_row = chi + (size_t)(mb * 64 + wv * 16 + li) * DD + quad * 8;
    const u16* al_row = clo + (size_t)(mb * 64 + wv * 16 + li) * DD + quad * 8;
    const size_t wboff = (size_t)nb * 65536 + (size_t)lane * 8;

    for (int kc = 0; kc < 8; ++kc) {
        const u16* wb_h = whi + wboff + kc * 8192;
        const u16* wb_l = wlo + wboff + kc * 8192;
        #pragma unroll
        for (int c = 0; c < 4; ++c) {
            bf16x8 ah = *(const bf16x8*)(ah_row + kc * 128 + c * 32);
            bf16x8 al = *(const bf16x8*)(al_row + kc * 128 + c * 32);
            bf16x8 bh0 = *(const bf16x8*)(wb_h + c * 512);
            bf16x8 bl0 = *(const bf16x8*)(wb_l + c * 512);
            bf16x8 bh1 = *(const bf16x8*)(wb_h + 2048 + c * 512);
            bf16x8 bl1 = *(const bf16x8*)(wb_l + 2048 + c * 512);
            bf16x8 bh2 = *(const bf16x8*)(wb_h + 4096 + c * 512);
            bf16x8 bl2 = *(const bf16x8*)(wb_l + 4096 + c * 512);
            bf16x8 bh3 = *(const bf16x8*)(wb_h + 6144 + c * 512);
            bf16x8 bl3 = *(const bf16x8*)(wb_l + 6144 + c * 512);
            acc0 = __builtin_amdgcn_mfma_f32_16x16x32_bf16(ah, bh0, acc0, 0, 0, 0);
            acc0 = __builtin_amdgcn_mfma_f32_16x16x32_bf16(ah, bl0, acc0, 0, 0, 0);
            acc0 = __builtin_amdgcn_mfma_f32_16x16x32_bf16(al, bh0, acc0, 0, 0, 0);
            acc1 = __builtin_amdgcn_mfma_f32_16x16x32_bf16(ah, bh1, acc1, 0, 0, 0);
            acc1 = __builtin_amdgcn_mfma_f32_16x16x32_bf16(ah, bl1, acc1, 0, 0, 0);
            acc1 = __builtin_amdgcn_mfma_f32_16x16x32_bf16(al, bh1, acc1, 0, 0, 0);
            acc2 = __builtin_amdgcn_mfma_f32_16x16x32_bf16(ah, bh2, acc2, 0, 0, 0);
            acc2 = __builtin_amdgcn_mfma_f32_16x16x32_bf16(ah, bl2, acc2, 0, 0, 0);
            acc2 = __builtin_amdgcn_mfma_f32_16x16x32_bf16(al, bh2, acc2, 0, 0, 0);
            acc3 = __builtin_amdgcn_mfma_f32_16x16x32_bf16(ah, bh3, acc3, 0, 0, 0);
            acc3 = __builtin_amdgcn_mfma_f32_16x16x32_bf16(ah, bl3, acc3, 0, 0, 0);
            acc3 = __builtin_amdgcn_mfma_f32_16x16x32_bf16(al, bh3, acc3, 0, 0, 0);
        }
    }

    #pragma unroll
    for (int st = 0; st < 4; ++st) {
        f32x4 a = (st == 0) ? acc0 : (st == 1) ? acc1 : (st == 2) ? acc2 : acc3;
        int col = nb * 64 + st * 16 + li;
        float bb2 = bias[col];
        #pragma unroll
        for (int r = 0; r < 4; ++r)
            out[(size_t)(mb * 64 + wv * 16 + quad * 4 + r) * DD + col] = a[r] + bb2;
    }
}

// ===========================================================================
// FALLBACK PATH (unchanged from previous passing version)
// ===========================================================================

__global__ __launch_bounds__(256) void attn_kernel(
    const float* __restrict__ q, const float* __restrict__ k, const float* __restrict__ v,
    float* __restrict__ aw, float* __restrict__ ctx)
{
    const int bid  = blockIdx.x;
    const int qt   = bid & 31;
    const int h    = (bid >> 5) & 15;
    const int b    = bid >> 9;
    const int t    = threadIdx.x;
    const int wv   = t >> 6;
    const int lane = t & 63;
    const int li   = lane & 15;
    const int quad = lane >> 4;

    __shared__ __align__(16) char smA[32768];
    __shared__ float s2v[32][4][8];
    __shared__ int   s2i[32][4][8];
    __shared__ int   cidx[32][12];
    __shared__ float cs[32][12];
    __shared__ float wrow[64][8];
    __shared__ int   wix[64][8];
    u16* khi = (u16*)smA;
    u16* klo = (u16*)(smA + 16384);

    const float* kbase = k + ((size_t)b * LL) * DD + h * 64;
    f32x4* awz = (f32x4*)(aw + (((size_t)(b * HH + h) * LL) + (size_t)qt * 64) * LL);
    const f32x4 zero4 = {0.f, 0.f, 0.f, 0.f};

    bf16x8 qh0, ql0, qh1, ql1;
    {
        const float* qrow = q + ((size_t)(b * LL + qt * 64 + wv * 16 + li)) * DD + h * 64;
        float x[8];
        *(f32x4*)x       = *(const f32x4*)(qrow + quad * 8);
        *(f32x4*)(x + 4) = *(const f32x4*)(qrow + quad * 8 + 4);
        #pragma unroll
        for (int e = 0; e < 8; ++e) { short hh, ll; splitbf(x[e], hh, ll); qh0[e] = hh; ql0[e] = ll; }
        *(f32x4*)x       = *(const f32x4*)(qrow + 32 + quad * 8);
        *(f32x4*)(x + 4) = *(const f32x4*)(qrow + 32 + quad * 8 + 4);
        #pragma unroll
        for (int e = 0; e < 8; ++e) { short hh, ll; splitbf(x[e], hh, ll); qh1[e] = hh; ql1[e] = ll; }
    }

    float tv[4][8]; int tix[4][8];
    #pragma unroll
    for (int r = 0; r < 4; ++r)
        #pragma unroll
        for (int s = 0; s < 8; ++s) { tv[r][s] = -INFINITY; tix[r][s] = 0; }

    for (int iter = 0; iter < 16; ++iter) {
        __syncthreads();
        #pragma unroll
        for (int j = 0; j < 4; ++j) {
            int f   = j * 256 + t;
            int col = f >> 3;
            int c   = (f >> 2) & 1;
            int qd  = f & 3;
            const float* src = kbase + (size_t)(iter * 128 + col) * DD + c * 32 + qd * 8;
            float x[8];
            *(f32x4*)x       = *(const f32x4*)src;
            *(f32x4*)(x + 4) = *(const f32x4*)(src + 4);
            bf16x8 h8, l8;
            #pragma unroll
            for (int e = 0; e < 8; ++e) { short hh, ll; splitbf(x[e], hh, ll); h8[e] = hh; l8[e] = ll; }
            int off = (((col >> 4) * 2 + c) << 9) + (qd << 7) + ((col & 15) << 3);
            *(bf16x8*)&khi[off] = h8;
            *(bf16x8*)&klo[off] = l8;
        }
        #pragma unroll
        for (int i = 0; i < 8; ++i) awz[iter * 2048 + i * 256 + t] = zero4;
        __syncthreads();

        #pragma unroll
        for (int s = 0; s < 8; ++s) {
            int fo = s << 10;
            bf16x8 kh0 = *(bf16x8*)&khi[fo + (lane << 3)];
            bf16x8 kh1 = *(bf16x8*)&khi[fo + 512 + (lane << 3)];
            bf16x8 kl0 = *(bf16x8*)&klo[fo + (lane << 3)];
            bf16x8 kl1 = *(bf16x8*)&klo[fo + 512 + (lane << 3)];
            f32x4 c4 = {0.f, 0.f, 0.f, 0.f};
            c4 = __builtin_amdgcn_mfma_f32_16x16x32_bf16(qh0, kh0, c4, 0, 0, 0);
            c4 = __builtin_amdgcn_mfma_f32_16x16x32_bf16(qh1, kh1, c4, 0, 0, 0);
            c4 = __builtin_amdgcn_mfma_f32_16x16x32_bf16(qh0, kl0, c4, 0, 0, 0);
            c4 = __builtin_amdgcn_mfma_f32_16x16x32_bf16(qh1, kl1, c4, 0, 0, 0);
            c4 = __builtin_amdgcn_mfma_f32_16x16x32_bf16(ql0, kh0, c4, 0, 0, 0);
            c4 = __builtin_amdgcn_mfma_f32_16x16x32_bf16(ql1, kh1, c4, 0, 0, 0);
            int ci = iter * 128 + s * 16 + li;
            #pragma unroll
            for (int r = 0; r < 4; ++r) {
                float cv = c4[r] * SCALE;
                if (cv > tv[r][7]) insert8(tv[r], tix[r], cv, ci);
            }
        }
    }

    float* mv = (float*)smA;
    int*   mi = (int*)(smA + 16384);
    for (int bb = 0; bb < 2; ++bb) {
        __syncthreads();
        if ((wv >> 1) == bb) {
            int rl0 = (wv & 1) * 16 + quad * 4;
            #pragma unroll
            for (int r = 0; r < 4; ++r) {
                int base = (rl0 + r) * 128 + li * 8;
                #pragma unroll
                for (int s = 0; s < 8; ++s) { mv[base + s] = tv[r][s]; mi[base + s] = tix[r][s]; }
            }
        }
        __syncthreads();
        if (t < 128) {
            int rr = t >> 2, p = t & 3;
            int base = rr * 128 + p * 32;
            merge4(&mv[base], &mi[base], &mv[base + 8], &mi[base + 8],
                   &mv[base + 16], &mi[base + 16], &mv[base + 24], &mi[base + 24],
                   s2v[rr][p], s2i[rr][p]);
        }
        __syncthreads();
        if (t < 32) {
            int rr = t;
            int pp[4] = {0, 0, 0, 0};
            #pragma unroll
            for (int s = 0; s < 12; ++s) {
                float bv = -INFINITY; int bi = 0x7fffffff; int bc = 0;
                #pragma unroll
                for (int l = 0; l < 4; ++l) {
                    if (pp[l] < 8) {
                        float hv = s2v[rr][l][pp[l]]; int hi2 = s2i[rr][l][pp[l]];
                        if (hv > bv || (hv == bv && hi2 < bi)) { bv = hv; bi = hi2; bc = l; }
                    }
                }
                pp[bc] += 1;
                cidx[rr][s] = bi;
            }
        }
        __syncthreads();
        for (int task = t; task < 384; task += 256) {
            int row = task / 12, c = task - row * 12;
            const float* qp = q + ((size_t)(b * LL + qt * 64 + bb * 32 + row)) * DD + h * 64;
            const float* kp = k + ((size_t)(b * LL + cidx[row][c])) * DD + h * 64;
            float acc = 0.f;
            for (int d4 = 0; d4 < 16; ++d4) {
                f32x4 qa = *(const f32x4*)(qp + d4 * 4);
                f32x4 ka = *(const f32x4*)(kp + d4 * 4);
                acc = fmaf(qa[0], ka[0], acc);
                acc = fmaf(qa[1], ka[1], acc);
                acc = fmaf(qa[2], ka[2], acc);
                acc = fmaf(qa[3], ka[3], acc);
            }
            cs[row][c] = acc * SCALE;
        }
        __syncthreads();
        if (t < 32) {
            int rr = t;
            float vv[12]; int ii[12];
            #pragma unroll
            for (int c = 0; c < 12; ++c) { vv[c] = cs[rr][c]; ii[c] = cidx[rr][c]; }
            float fv[8]; int fi[8];
            #pragma unroll
            for (int s = 0; s < 8; ++s) {
                float bv = -INFINITY; int bi = 0x7fffffff; int bc = 0;
                #pragma unroll
                for (int c = 0; c < 12; ++c) {
                    if (vv[c] > bv || (vv[c] == bv && ii[c] < bi)) { bv = vv[c]; bi = ii[c]; bc = c; }
                }
                vv[bc] = -INFINITY;
                fv[s] = bv; fi[s] = bi;
            }
            float m = fv[0];
            float e0[8]; float sum = 0.f;
            #pragma unroll
            for (int s = 0; s < 8; ++s) { e0[s] = __expf(fv[s] - m); sum += e0[s]; }
            float inv = 1.0f / sum;
            int grow = bb * 32 + rr;
            float* awrow = aw + (((size_t)(b * HH + h) * LL) + (size_t)qt * 64 + grow) * LL;
            #pragma unroll
            for (int s = 0; s < 8; ++s) {
                float w8 = e0[s] * inv;
                awrow[fi[s]] = w8;
                wrow[grow][s] = w8; wix[grow][s] = fi[s];
            }
        }
    }
    __syncthreads();

    const float* vbase = v + ((size_t)b * LL) * DD + h * 64;
    #pragma unroll
    for (int i = 0; i < 4; ++i) {
        int id = i * 256 + t;
        int row = id >> 4, seg = id & 15;
        f32x4 acc = {0.f, 0.f, 0.f, 0.f};
        #pragma unroll
        for (int s = 0; s < 8; ++s) {
            float ws = wrow[row][s];
            f32x4 vvv = *(const f32x4*)(vbase + (size_t)wix[row][s] * DD + seg * 4);
            acc[0] = fmaf(ws, vvv[0], acc[0]);
            acc[1] = fmaf(ws, vvv[1], acc[1]);
            acc[2] = fmaf(ws, vvv[2], acc[2]);
            acc[3] = fmaf(ws, vvv[3], acc[3]);
        }
        *(f32x4*)(ctx + ((size_t)(b * LL + qt * 64 + row)) * DD + h * 64 + seg * 4) = acc;
    }
}

__global__ __launch_bounds__(256) void linear_ws_kernel(
    const float* __restrict__ ctx, const float* __restrict__ w,
    const float* __restrict__ bias, float* __restrict__ out)
{
    const int bid  = blockIdx.x;
    const int nb   = bid & 15, mb = bid >> 4;
    const int t    = threadIdx.x;
    const int wv   = t >> 6;
    const int lane = t & 63;
    const int li   = lane & 15;
    const int quad = lane >> 4;

    __shared__ u16 bhi[8192], blo[8192];

    f32x4 acc0 = {0.f,0.f,0.f,0.f}, acc1 = {0.f,0.f,0.f,0.f},
          acc2 = {0.f,0.f,0.f,0.f}, acc3 = {0.f,0.f,0.f,0.f};
    const float* arow = ctx + (size_t)(mb * 64 + wv * 16 + li) * DD;

    for (int kc = 0; kc < 8; ++kc) {
        __syncthreads();
        #pragma unroll
        for (int j = 0; j < 4; ++j) {
            int f   = j * 256 + t;
            int col = f >> 4;
            int c   = (f >> 2) & 3;
            int qd  = f & 3;
            const float* src = w + (size_t)(nb * 64 + col) * DD + kc * 128 + c * 32 + qd * 8;
            float x[8];
            *(f32x4*)x       = *(const f32x4*)src;
            *(f32x4*)(x + 4) = *(const f32x4*)(src + 4);
            bf16x8 h8, l8;
            #pragma unroll
            for (int e = 0; e < 8; ++e) { short hh, ll; splitbf(x[e], hh, ll); h8[e] = hh; l8[e] = ll; }
            int off = (((col >> 4) * 4 + c) << 9) + (qd << 7) + ((col & 15) << 3);
            *(bf16x8*)&bhi[off] = h8;
            *(bf16x8*)&blo[off] = l8;
        }
        __syncthreads();

        bf16x8 ah[4], al[4];
        #pragma unroll
        for (int c = 0; c < 4; ++c) {
            float x[8];
            *(f32x4*)x       = *(const f32x4*)(arow + kc * 128 + c * 32 + quad * 8);
            *(f32x4*)(x + 4) = *(const f32x4*)(arow + kc * 128 + c * 32 + quad * 8 + 4);
            #pragma unroll
            for (int e = 0; e < 8; ++e) { short hh, ll; splitbf(x[e], hh, ll); ah[c][e] = hh; al[c][e] = ll; }
        }
        #pragma unroll
        for (int c = 0; c < 4; ++c) {
            bf16x8 bh0 = *(bf16x8*)&bhi[(( 0 + c) << 9) + (lane << 3)];
            bf16x8 bl0 = *(bf16x8*)&blo[(( 0 + c) << 9) + (lane << 3)];
            bf16x8 bh1 = *(bf16x8*)&bhi[(( 4 + c) << 9) + (lane << 3)];
            bf16x8 bl1 = *(bf16x8*)&blo[(( 4 + c) << 9) + (lane << 3)];
            bf16x8 bh2 = *(bf16x8*)&bhi[(( 8 + c) << 9) + (lane << 3)];
            bf16x8 bl2 = *(bf16x8*)&blo[(( 8 + c) << 9) + (lane << 3)];
            bf16x8 bh3 = *(bf16x8*)&bhi[((12 + c) << 9) + (lane << 3)];
            bf16x8 bl3 = *(bf16x8*)&blo[((12 + c) << 9) + (lane << 3)];
            acc0 = __builtin_amdgcn_mfma_f32_16x16x32_bf16(ah[c], bh0, acc0, 0, 0, 0);
            acc0 = __builtin_amdgcn_mfma_f32_16x16x32_bf16(ah[c], bl0, acc0, 0, 0, 0);
            acc0 = __builtin_amdgcn_mfma_f32_16x16x32_bf16(al[c], bh0, acc0, 0, 0, 0);
            acc1 = __builtin_amdgcn_mfma_f32_16x16x32_bf16(ah[c], bh1, acc1, 0, 0, 0);
            acc1 = __builtin_amdgcn_mfma_f32_16x16x32_bf16(ah[c], bl1, acc1, 0, 0, 0);
            acc1 = __builtin_amdgcn_mfma_f32_16x16x32_bf16(al[c], bh1, acc1, 0, 0, 0);
            acc2 = __builtin_amdgcn_mfma_f32_16x16x32_bf16(ah[c], bh2, acc2, 0, 0, 0);
            acc2 = __builtin_amdgcn_mfma_f32_16x16x32_bf16(ah[c], bl2, acc2, 0, 0, 0);
            acc2 = __builtin_amdgcn_mfma_f32_16x16x32_bf16(al[c], bh2, acc2, 0, 0, 0);
            acc3 = __builtin_amdgcn_mfma_f32_16x16x32_bf16(ah[c], bh3, acc3, 0, 0, 0);
            acc3 = __builtin_amdgcn_mfma_f32_16x16x32_bf16(ah[c], bl3, acc3, 0, 0, 0);
            acc3 = __builtin_amdgcn_mfma_f32_16x16x32_bf16(al[c], bh3, acc3, 0, 0, 0);
        }
    }

    #pragma unroll
    for (int st = 0; st < 4; ++st) {
        f32x4 a = (st == 0) ? acc0 : (st == 1) ? acc1 : (st == 2) ? acc2 : acc3;
        int col = nb * 64 + st * 16 + li;
        float bb2 = bias[col];
        #pragma unroll
        for (int r = 0; r < 4; ++r)
            out[(size_t)(mb * 64 + wv * 16 + quad * 4 + r) * DD + col] = a[r] + bb2;
    }
}

__global__ __launch_bounds__(256) void linear_inplace_kernel(
    float* io, const float* __restrict__ w, const float* __restrict__ bias)
{
    __shared__ u16 ahi[16384], alo[16384];
    const int t    = threadIdx.x;
    const int m0   = blockIdx.x * 16;
    const int wv   = t >> 6;
    const int lane = t & 63;
    const int li   = lane & 15;
    const int quad = lane >> 4;

    #pragma unroll
    for (int i = 0; i < 8; ++i) {
        int id  = i * 256 + t;
        int row = id >> 7;
        int c   = (id >> 2) & 31;
        int qd  = id & 3;
        const float* src = io + (size_t)(m0 + row) * DD + c * 32 + qd * 8;
        float x[8];
        *(f32x4*)x       = *(const f32x4*)src;
        *(f32x4*)(x + 4) = *(const f32x4*)(src + 4);
        bf16x8 h8, l8;
        #pragma unroll
        for (int e = 0; e < 8; ++e) { short hh, ll; splitbf(x[e], hh, ll); h8[e] = hh; l8[e] = ll; }
        int off = (c << 9) + (qd << 7) + (row << 3);
        *(bf16x8*)&ahi[off] = h8;
        *(bf16x8*)&alo[off] = l8;
    }
    __syncthreads();

    f32x4 acc[16];
    #pragma unroll
    for (int i = 0; i < 16; ++i) acc[i] = (f32x4){0.f, 0.f, 0.f, 0.f};

    for (int c = 0; c < 32; ++c) {
        bf16x8 ah = *(bf16x8*)&ahi[(c << 9) + (lane << 3)];
        bf16x8 al = *(bf16x8*)&alo[(c << 9) + (lane << 3)];
        #pragma unroll
        for (int sub = 0; sub < 16; ++sub) {
            int col = wv * 256 + sub * 16 + li;
            const float* src = w + (size_t)col * DD + c * 32 + quad * 8;
            float x[8];
            *(f32x4*)x       = *(const f32x4*)src;
            *(f32x4*)(x + 4) = *(const f32x4*)(src + 4);
            bf16x8 bh, bl;
            #pragma unroll
            for (int e = 0; e < 8; ++e) { short hh, ll; splitbf(x[e], hh, ll); bh[e] = hh; bl[e] = ll; }
            acc[sub] = __builtin_amdgcn_mfma_f32_16x16x32_bf16(ah, bh, acc[sub], 0, 0, 0);
            acc[sub] = __builtin_amdgcn_mfma_f32_16x16x32_bf16(ah, bl, acc[sub], 0, 0, 0);
            acc[sub] = __builtin_amdgcn_mfma_f32_16x16x32_bf16(al, bh, acc[sub], 0, 0, 0);
        }
    }

    #pragma unroll
    for (int sub = 0; sub < 16; ++sub) {
        int col = wv * 256 + sub * 16 + li;
        float bb2 = bias[col];
        #pragma unroll
        for (int r = 0; r < 4; ++r)
            io[(size_t)(m0 + quad * 4 + r) * DD + col] = acc[sub][r] + bb2;
    }
}

extern "C" void kernel_launch(void* const* d_in, const int* in_sizes, int n_in,
                              void* d_out, int out_size, void* d_ws, size_t ws_size,
                              hipStream_t stream) {
    const float* q    = (const float*)d_in[0];
    const float* k    = (const float*)d_in[1];
    const float* v    = (const float*)d_in[2];
    const float* w    = (const float*)d_in[3];
    const float* bias = (const float*)d_in[4];

    float* out = (float*)d_out;                  // attn_out [B*L*D]
    float* aw  = out + ATTN_ELEMS;               // attn_weights [B*H*L*L]

    const size_t CHI_ELE = ATTN_ELEMS;           // shorts (ctx split)
    const size_t KSP_ELE = 4194304;              // shorts (k split, fragment layout)
    const size_t WSP_ELE = 1048576;              // shorts (w split, fragment layout)
    const size_t need_fast = (2 * CHI_ELE + 2 * KSP_ELE + 2 * WSP_ELE) * sizeof(u16); // 36 MB

    if (d_ws != nullptr && ws_size >= need_fast) {
        u16* chi = (u16*)d_ws;
        u16* clo = chi + CHI_ELE;
        u16* khi = clo + CHI_ELE;
        u16* klo = khi + KSP_ELE;
        u16* whi = klo + KSP_ELE;
        u16* wlo = whi + WSP_ELE;
        prep_k_kernel<<<2048, 256, 0, stream>>>(k, khi, klo);
        prep_w_kernel<<<512, 256, 0, stream>>>(w, whi, wlo);
        attn_fast_kernel<<<BB * HH * (LL / 64), 256, 0, stream>>>(q, k, v, khi, klo, aw, chi, clo);
        linear_fast_kernel<<<(BB * LL / 64) * (DD / 64), 256, 0, stream>>>(chi, clo, whi, wlo, bias, out);
    } else {
        const bool use_ws = (d_ws != nullptr) && (ws_size >= ATTN_ELEMS * sizeof(float));
        float* ctx = use_ws ? (float*)d_ws : out;
        attn_kernel<<<BB * HH * (LL / 64), 256, 0, stream>>>(q, k, v, aw, ctx);
        if (use_ws) {
            linear_ws_kernel<<<(BB * LL / 64) * (DD / 64), 256, 0, stream>>>(ctx, w, bias, out);
        } else {
            linear_inplace_kernel<<<BB * LL / 16, 256, 0, stream>>>(out, w, bias);
        }
    }
}